// Round 2
// baseline (6629.265 us; speedup 1.0000x reference)
//
#include <hip/hip_runtime.h>
#include <stdint.h>

#define T_ 512
#define B_ 64
#define E_ 256
#define H_ 512
#define KT 50

typedef __attribute__((ext_vector_type(8))) short bf16x8;
typedef __attribute__((ext_vector_type(4))) float f32x4;
typedef __attribute__((ext_vector_type(4))) int i32x4;

#define MFMA16(a,b,c) __builtin_amdgcn_mfma_f32_16x16x32_bf16((a),(b),(c),0,0,0)

static __device__ __forceinline__ float bf2f(unsigned short v) {
  unsigned int u = ((unsigned int)v) << 16; float f; __builtin_memcpy(&f, &u, 4); return f;
}
static __device__ __forceinline__ unsigned short f2bf(float f) {
  unsigned int u; __builtin_memcpy(&u, &f, 4);
  u += 0x7fffu + ((u >> 16) & 1u);
  return (unsigned short)(u >> 16);
}
static __device__ __forceinline__ float sigm(float x) { return 1.f / (1.f + __expf(-x)); }
static __device__ __forceinline__ float tanh_(float x) { return 2.f / (1.f + __expf(-2.f * x)) - 1.f; }

// ------------------------------------------------------------- dtype probe
// Even-index ushorts of a bf16 array are real bf16 values (|v| in [1e-8,4]
// w.p. ~1 for N(0,0.1)); of an f32 array they are random mantissa halves
// (in-range w.p. ~0.09). Majority vote over 64 lanes.
__global__ void probe_kernel(const unsigned short* __restrict__ e,
                             unsigned int* __restrict__ flag) {
  int lane = threadIdx.x & 63;
  float a = fabsf(bf2f(e[2 * lane]));
  int good = (a >= 1e-8f && a <= 4.0f);
  unsigned long long m = __ballot(good);
  if (threadIdx.x == 0) flag[0] = (__popcll(m) >= 48) ? 1u : 0u;
}

// ------------------------------------------------------------- canonicalize
struct CvtArgs { const void* src; unsigned short* dst; int n; };
struct CvtPack { CvtArgs a[11]; };

__global__ __launch_bounds__(256) void convert_kernel(CvtPack p,
                                                      const unsigned int* __restrict__ flag) {
  CvtArgs c = p.a[blockIdx.y];
  int i = (blockIdx.x * 256 + threadIdx.x) * 8;
  if (i >= c.n) return;
  int isbf = *flag;
  if (i + 8 <= c.n) {
    if (isbf) {
      *(i32x4*)(c.dst + i) = *(const i32x4*)((const unsigned short*)c.src + i);
    } else {
      const float* s = (const float*)c.src;
      float4 a0 = *(const float4*)(s + i);
      float4 a1 = *(const float4*)(s + i + 4);
      unsigned short o[8] = {f2bf(a0.x), f2bf(a0.y), f2bf(a0.z), f2bf(a0.w),
                             f2bf(a1.x), f2bf(a1.y), f2bf(a1.z), f2bf(a1.w)};
      *(i32x4*)(c.dst + i) = *(i32x4*)o;
    }
  } else {
    for (int j = 0; j < 8; j++) {
      if (i + j < c.n) {
        c.dst[i + j] = isbf ? ((const unsigned short*)c.src)[i + j]
                            : f2bf(((const float*)c.src)[i + j]);
      }
    }
  }
}

// ---------------------------------------------------------------- embedding
__global__ __launch_bounds__(256) void embed_kernel(
    const int* __restrict__ tokens, const void* __restrict__ embed,
    const unsigned int* __restrict__ flag, unsigned short* __restrict__ x) {
  int tid = threadIdx.x;
  int row = blockIdx.x * 8 + (tid >> 5);   // row = t*64+b, 32768 rows
  int l = tid & 31;
  int tok = tokens[row];
  if (*flag) {
    const unsigned short* e = (const unsigned short*)embed;
    *(i32x4*)(x + (size_t)row * E_ + l * 8) =
        *(const i32x4*)(e + (size_t)tok * E_ + l * 8);
  } else {
    const float* e = (const float*)embed + (size_t)tok * E_ + l * 8;
    float4 a0 = *(const float4*)e;
    float4 a1 = *(const float4*)(e + 4);
    unsigned short o[8] = {f2bf(a0.x), f2bf(a0.y), f2bf(a0.z), f2bf(a0.w),
                           f2bf(a1.x), f2bf(a1.y), f2bf(a1.z), f2bf(a1.w)};
    *(i32x4*)(x + (size_t)row * E_ + l * 8) = *(i32x4*)o;
  }
}

// ---------------------------------------------------------------- BiLSTM
// 128 blocks; each WG owns 8 hidden units (32 gate rows). Weights pinned in
// VGPRs as MFMA A-fragments; waves split K (768 = 512 h + 256 x). Cross-WG h
// handoff: agent-scope atomic dword stores + flags; consumers use agent-scope
// atomic loads (coherent point) so no stale L1/L2 lines can be served.
__global__ __launch_bounds__(256) void lstm_kernel(
    const unsigned short* __restrict__ whh_f, const unsigned short* __restrict__ wih_f,
    const unsigned short* __restrict__ bias_f,
    const unsigned short* __restrict__ whh_b, const unsigned short* __restrict__ wih_b,
    const unsigned short* __restrict__ bias_b,
    const unsigned short* __restrict__ x,
    unsigned short* __restrict__ hf, unsigned short* __restrict__ hb,
    unsigned int* __restrict__ flags) {
  const int tid = threadIdx.x;
  const int wv = tid >> 6, lane = tid & 63, q = lane >> 4, l15 = lane & 15;
  const int bid = blockIdx.x;
  const int dir = (bid >> 2) & 1;                 // (bid%8)<4 ? 0 : 1
  const int wg = (bid >> 3) * 4 + (bid & 3);      // 0..63 within direction
  const int u0 = wg * 8;

  const unsigned short* whh = dir ? whh_b : whh_f;
  const unsigned short* wih = dir ? wih_b : wih_f;
  const unsigned short* bvec = dir ? bias_b : bias_f;
  unsigned short* hbuf = dir ? hb : hf;
  unsigned int* flg = flags + (size_t)dir * T_ * 64;

  // ---- preload weight A-fragments (rows: [i0..7 f0..7] mt0, [g0..7 o0..7] mt1)
  bf16x8 afrag[2][6];
#pragma unroll
  for (int mt = 0; mt < 2; mt++) {
    int base = (mt == 0) ? ((l15 < 8) ? 0 : 512) : ((l15 < 8) ? 1024 : 1536);
    int row = base + u0 + (l15 & 7);
#pragma unroll
    for (int kl = 0; kl < 6; kl++) {
      int kc = wv * 6 + kl;
      const unsigned short* p = (kc < 16)
          ? (whh + (size_t)row * H_ + kc * 32 + q * 8)
          : (wih + (size_t)row * E_ + (kc - 16) * 32 + q * 8);
      afrag[mt][kl] = *(const bf16x8*)p;
    }
  }

  const int eb = tid & 63;
  const int uu = tid >> 6;
  float bg[2][4];
#pragma unroll
  for (int s = 0; s < 2; s++) {
    int u = uu + 4 * s;
#pragma unroll
    for (int g = 0; g < 4; g++) bg[s][g] = bf2f(bvec[g * H_ + u0 + u]);
  }
  float cst[2] = {0.f, 0.f};

  __shared__ float pacc[4][32][66];
  __shared__ __align__(16) unsigned short h_out[64][8];

  for (int step = 0; step < T_; step++) {
    const int t = dir ? (T_ - 1 - step) : step;
    f32x4 acc0[4], acc1[4];
#pragma unroll
    for (int nt = 0; nt < 4; nt++) {
      acc0[nt] = (f32x4){0.f, 0.f, 0.f, 0.f};
      acc1[nt] = (f32x4){0.f, 0.f, 0.f, 0.f};
    }

    // x-part (no dependency on h): kc >= 16
    {
      const unsigned short* xb = x + (size_t)t * B_ * E_;
#pragma unroll
      for (int kl = 0; kl < 6; kl++) {
        int kc = wv * 6 + kl;
        if (kc >= 16) {
#pragma unroll
          for (int nt = 0; nt < 4; nt++) {
            int b = nt * 16 + l15;
            bf16x8 bx = *(const bf16x8*)(xb + (size_t)b * E_ + (kc - 16) * 32 + q * 8);
            acc0[nt] = MFMA16(afrag[0][kl], bx, acc0[nt]);
            acc1[nt] = MFMA16(afrag[1][kl], bx, acc1[nt]);
          }
        }
      }
    }

    if (step > 0) {
      if (wv * 6 < 16) {  // waves holding h-k-chunks: acquire previous h
        unsigned int* fp = flg + (size_t)(step - 1) * 64 + lane;
        while (!__all(__hip_atomic_load(fp, __ATOMIC_RELAXED,
                                        __HIP_MEMORY_SCOPE_AGENT) != 0))
          __builtin_amdgcn_s_sleep(1);
        asm volatile("" ::: "memory");  // no hoisting of h loads above the wait
      }
      const int tprev = dir ? (t + 1) : (t - 1);
      const unsigned int* h32 = (const unsigned int*)(hbuf + (size_t)tprev * B_ * H_);
#pragma unroll
      for (int kl = 0; kl < 6; kl++) {
        int kc = wv * 6 + kl;
        if (kc < 16) {
#pragma unroll
          for (int nt = 0; nt < 4; nt++) {
            int b = nt * 16 + l15;
            unsigned int* p = (unsigned int*)(h32 + ((b * H_ + kc * 32 + q * 8) >> 1));
            union { unsigned int u[4]; bf16x8 v; } cv;
#pragma unroll
            for (int d = 0; d < 4; d++)
              cv.u[d] = __hip_atomic_load(p + d, __ATOMIC_RELAXED,
                                          __HIP_MEMORY_SCOPE_AGENT);
            acc0[nt] = MFMA16(afrag[0][kl], cv.v, acc0[nt]);
            acc1[nt] = MFMA16(afrag[1][kl], cv.v, acc1[nt]);
          }
        }
      }
    }

    __syncthreads();
#pragma unroll
    for (int nt = 0; nt < 4; nt++) {
      int b = nt * 16 + l15;
#pragma unroll
      for (int r = 0; r < 4; r++) {
        pacc[wv][q * 4 + r][b] = acc0[nt][r];
        pacc[wv][16 + q * 4 + r][b] = acc1[nt][r];
      }
    }
    __syncthreads();

#pragma unroll
    for (int s = 0; s < 2; s++) {
      int u = uu + 4 * s;
      float gi = bg[s][0], gf = bg[s][1], gg = bg[s][2], go = bg[s][3];
#pragma unroll
      for (int w = 0; w < 4; w++) {
        gi += pacc[w][u][eb];
        gf += pacc[w][8 + u][eb];
        gg += pacc[w][16 + u][eb];
        go += pacc[w][24 + u][eb];
      }
      float cn = sigm(gf) * cst[s] + sigm(gi) * tanh_(gg);
      cst[s] = cn;
      float h = sigm(go) * tanh_(cn);
      h_out[eb][u] = f2bf(h);
    }
    __syncthreads();

    if (wv == 0) {  // publish h slice (agent scope) then release flag
      const unsigned int* hw = (const unsigned int*)&h_out[lane][0];
      unsigned int* gp = (unsigned int*)(hbuf + ((size_t)t * B_ + lane) * H_ + u0);
#pragma unroll
      for (int i = 0; i < 4; i++)
        __hip_atomic_store(gp + i, hw[i], __ATOMIC_RELAXED, __HIP_MEMORY_SCOPE_AGENT);
      asm volatile("s_waitcnt vmcnt(0)" ::: "memory");
      if (lane == 0) {
        unsigned int* fq = flg + (size_t)step * 64 + wg;
        __hip_atomic_store(fq, 1u, __ATOMIC_RELAXED, __HIP_MEMORY_SCOPE_AGENT);
      }
    }
  }
}

// ---------------------------------------------------------------- encoder GEMM
// states = tanh([hf|hb] @ w_enc^T + b_enc): M=32768, K=1024, N=512
__global__ __launch_bounds__(256) void enc_kernel(
    const unsigned short* __restrict__ hf, const unsigned short* __restrict__ hb,
    const unsigned short* __restrict__ w_enc, const unsigned short* __restrict__ b_enc,
    unsigned short* __restrict__ states) {
  const int tid = threadIdx.x;
  const int bm = blockIdx.x, bn = blockIdx.y;
  const int wv = tid >> 6, lane = tid & 63, q = lane >> 4, l15 = lane & 15;
  const int wm = wv >> 1, wn = wv & 1;

  __shared__ __align__(16) unsigned short a_lds[128][72];
  __shared__ __align__(16) unsigned short b_lds[128][72];
  __shared__ __align__(16) unsigned short st_lds[128][136];

  f32x4 acc[4][4];
#pragma unroll
  for (int mt = 0; mt < 4; mt++)
#pragma unroll
    for (int nt = 0; nt < 4; nt++) acc[mt][nt] = (f32x4){0.f, 0.f, 0.f, 0.f};

  for (int c = 0; c < 16; c++) {
    const unsigned short* asrc = (c < 8) ? hf : hb;
    int kof = (c & 7) * 64;
#pragma unroll
    for (int p = 0; p < 4; p++) {
      int u = tid + p * 256;
      int r = u >> 3, wu = u & 7;
      *(i32x4*)&a_lds[r][wu * 8] =
          *(const i32x4*)(asrc + (size_t)(bm * 128 + r) * H_ + kof + wu * 8);
      *(i32x4*)&b_lds[r][wu * 8] =
          *(const i32x4*)(w_enc + (size_t)(bn * 128 + r) * 1024 + c * 64 + wu * 8);
    }
    __syncthreads();
#pragma unroll
    for (int kk = 0; kk < 64; kk += 32) {
      bf16x8 af[4], bfr[4];
#pragma unroll
      for (int mt = 0; mt < 4; mt++)
        af[mt] = *(const bf16x8*)&a_lds[wm * 64 + mt * 16 + l15][kk + q * 8];
#pragma unroll
      for (int nt = 0; nt < 4; nt++)
        bfr[nt] = *(const bf16x8*)&b_lds[wn * 64 + nt * 16 + l15][kk + q * 8];
#pragma unroll
      for (int mt = 0; mt < 4; mt++)
#pragma unroll
        for (int nt = 0; nt < 4; nt++) acc[mt][nt] = MFMA16(af[mt], bfr[nt], acc[mt][nt]);
    }
    __syncthreads();
  }

  float be[4];
#pragma unroll
  for (int nt = 0; nt < 4; nt++)
    be[nt] = bf2f(b_enc[bn * 128 + wn * 64 + nt * 16 + l15]);
#pragma unroll
  for (int mt = 0; mt < 4; mt++)
#pragma unroll
    for (int nt = 0; nt < 4; nt++)
#pragma unroll
      for (int r = 0; r < 4; r++) {
        float v = tanh_(acc[mt][nt][r] + be[nt]);
        st_lds[wm * 64 + mt * 16 + q * 4 + r][wn * 64 + nt * 16 + l15] = f2bf(v);
      }
  __syncthreads();
#pragma unroll
  for (int p = 0; p < 8; p++) {
    int u = tid + p * 256;
    int r = u >> 4, w = u & 15;
    *(i32x4*)(states + (size_t)(bm * 128 + r) * H_ + bn * 128 + w * 8) =
        *(const i32x4*)&st_lds[r][w * 8];
  }
}

// ---------------------------------------------------------------- emit GEMM
// emit = states @ w_out^T + b_out: M=32768, K=512, N=50 (padded 64), fp32 out
__global__ __launch_bounds__(256) void emit_kernel(
    const unsigned short* __restrict__ states, const unsigned short* __restrict__ w_out,
    const unsigned short* __restrict__ b_out, float* __restrict__ emit) {
  const int tid = threadIdx.x;
  const int bm = blockIdx.x;
  const int wv = tid >> 6, lane = tid & 63, q = lane >> 4, l15 = lane & 15;
  const int wm = wv >> 1, wn = wv & 1;

  __shared__ __align__(16) unsigned short wo_lds[64][520];
  __shared__ __align__(16) unsigned short a_lds[128][72];

#pragma unroll
  for (int p = 0; p < 16; p++) {
    int u = tid + p * 256;
    int r = u >> 6, wu = u & 63;
    i32x4 v = {0, 0, 0, 0};
    if (r < KT) v = *(const i32x4*)(w_out + (size_t)r * H_ + wu * 8);
    *(i32x4*)&wo_lds[r][wu * 8] = v;
  }

  f32x4 acc[4][2];
#pragma unroll
  for (int mt = 0; mt < 4; mt++)
#pragma unroll
    for (int nt = 0; nt < 2; nt++) acc[mt][nt] = (f32x4){0.f, 0.f, 0.f, 0.f};

  for (int c = 0; c < 8; c++) {
    __syncthreads();
#pragma unroll
    for (int p = 0; p < 4; p++) {
      int u = tid + p * 256;
      int r = u >> 3, wu = u & 7;
      *(i32x4*)&a_lds[r][wu * 8] =
          *(const i32x4*)(states + (size_t)(bm * 128 + r) * H_ + c * 64 + wu * 8);
    }
    __syncthreads();
#pragma unroll
    for (int kk = 0; kk < 64; kk += 32) {
      bf16x8 af[4], bfr[2];
#pragma unroll
      for (int mt = 0; mt < 4; mt++)
        af[mt] = *(const bf16x8*)&a_lds[wm * 64 + mt * 16 + l15][kk + q * 8];
#pragma unroll
      for (int nt = 0; nt < 2; nt++)
        bfr[nt] = *(const bf16x8*)&wo_lds[wn * 32 + nt * 16 + l15][c * 64 + kk + q * 8];
#pragma unroll
      for (int mt = 0; mt < 4; mt++)
#pragma unroll
        for (int nt = 0; nt < 2; nt++) acc[mt][nt] = MFMA16(af[mt], bfr[nt], acc[mt][nt]);
    }
  }

  float bo[2];
#pragma unroll
  for (int nt = 0; nt < 2; nt++) {
    int n = wn * 32 + nt * 16 + l15;
    bo[nt] = (n < KT) ? bf2f(b_out[n]) : 0.f;
  }
#pragma unroll
  for (int mt = 0; mt < 4; mt++)
#pragma unroll
    for (int nt = 0; nt < 2; nt++) {
      int n = wn * 32 + nt * 16 + l15;
      if (n < KT) {
#pragma unroll
        for (int r = 0; r < 4; r++) {
          int m = bm * 128 + wm * 64 + mt * 16 + q * 4 + r;
          emit[(size_t)m * KT + n] = acc[mt][nt][r] + bo[nt];
        }
      }
    }
}

// ---------------------------------------------------------------- CRF forward
__global__ __launch_bounds__(256) void crf_kernel(
    const float* __restrict__ emit, const unsigned short* __restrict__ trans,
    const unsigned int* __restrict__ flag, void* __restrict__ out) {
  const int tid = threadIdx.x;
  const int wv = tid >> 6, lane = tid & 63;
  const int b = blockIdx.x * 4 + wv;
  const int jj = (lane < KT) ? lane : (KT - 1);

  float tr[KT];
  float mj = -1e30f;
#pragma unroll
  for (int i = 0; i < KT; i++) {
    tr[i] = bf2f(trans[jj * KT + i]);
    mj = fmaxf(mj, tr[i]);
  }
  float et[KT];
#pragma unroll
  for (int i = 0; i < KT; i++) et[i] = __expf(tr[i] - mj);
  float tr_stop = bf2f(trans[(KT - 1) * KT + jj]);

  float alpha = (lane == 0) ? 0.f : -1e30f;
  float e_next = emit[(size_t)b * KT + jj];

  for (int t = 0; t < T_; t++) {
    float e_cur = e_next;
    if (t < T_ - 1) e_next = emit[((size_t)(t + 1) * B_ + b) * KT + jj];
    float M = alpha;
#pragma unroll
    for (int off = 32; off; off >>= 1) M = fmaxf(M, __shfl_xor(M, off, 64));
    float p = __expf(alpha - M);
    float s = 0.f;
#pragma unroll
    for (int i = 0; i < KT; i++) {
      float pi = __uint_as_float(__builtin_amdgcn_readlane(__float_as_uint(p), i));
      s = __builtin_fmaf(et[i], pi, s);
    }
    float an = e_cur + mj + M + __logf(s);
    alpha = (lane < KT) ? an : -1e30f;
  }

  float v = (lane < KT) ? (alpha + tr_stop) : -1e30f;
  float M2 = v;
#pragma unroll
  for (int off = 32; off; off >>= 1) M2 = fmaxf(M2, __shfl_xor(M2, off, 64));
  float s2 = (lane < KT) ? __expf(v - M2) : 0.f;
#pragma unroll
  for (int off = 32; off; off >>= 1) s2 += __shfl_xor(s2, off, 64);
  float lz = M2 + __logf(s2);
  if (lane == 0) {
    if (*flag) ((unsigned short*)out)[b] = f2bf(lz);
    else ((float*)out)[b] = lz;
  }
}

// ---------------------------------------------------------------- launch
extern "C" void kernel_launch(void* const* d_in, const int* in_sizes, int n_in,
                              void* d_out, int out_size, void* d_ws, size_t ws_size,
                              hipStream_t stream) {
  const int* tokens = (const int*)d_in[0];
  const void* embed = d_in[1];
  const void* wih_f = d_in[2];
  const void* whh_f = d_in[3];
  const void* b_f = d_in[4];
  const void* wih_b = d_in[5];
  const void* whh_b = d_in[6];
  const void* b_b = d_in[7];
  const void* w_enc = d_in[8];
  const void* b_enc = d_in[9];
  const void* w_out = d_in[10];
  const void* b_out = d_in[11];
  const void* trans = d_in[12];

  char* ws = (char*)d_ws;
  unsigned int* flags = (unsigned int*)ws;                       // 262144 B
  unsigned int* pflag = (unsigned int*)(ws + 262144);            // 256 B
  unsigned short* xbuf = (unsigned short*)(ws + 262400);         // 16 MB
  unsigned short* hf = (unsigned short*)(ws + 17039616);         // 32 MB
  unsigned short* hb = (unsigned short*)(ws + 50594048);         // 32 MB
  unsigned short* states = (unsigned short*)(ws + 84148480);     // 32 MB
  float* emit = (float*)(ws + 117702912);                        // 6.55 MB
  unsigned short* canon = (unsigned short*)(ws + 124256512);     // 7.4 MB

  // canonical bf16 copies (element offsets)
  unsigned short* c_wih_f = canon + 0;
  unsigned short* c_whh_f = canon + 524288;
  unsigned short* c_b_f   = canon + 1572864;
  unsigned short* c_wih_b = canon + 1574912;
  unsigned short* c_whh_b = canon + 2099200;
  unsigned short* c_b_b   = canon + 3147776;
  unsigned short* c_w_enc = canon + 3149824;
  unsigned short* c_b_enc = canon + 3674112;
  unsigned short* c_w_out = canon + 3674624;
  unsigned short* c_b_out = canon + 3700224;
  unsigned short* c_trans = canon + 3700352;

  hipMemsetAsync(flags, 0, 262144, stream);
  probe_kernel<<<1, 64, 0, stream>>>((const unsigned short*)embed, pflag);

  CvtPack pk;
  pk.a[0]  = {wih_f, c_wih_f, 524288};
  pk.a[1]  = {whh_f, c_whh_f, 1048576};
  pk.a[2]  = {b_f,   c_b_f,   2048};
  pk.a[3]  = {wih_b, c_wih_b, 524288};
  pk.a[4]  = {whh_b, c_whh_b, 1048576};
  pk.a[5]  = {b_b,   c_b_b,   2048};
  pk.a[6]  = {w_enc, c_w_enc, 524288};
  pk.a[7]  = {b_enc, c_b_enc, 512};
  pk.a[8]  = {w_out, c_w_out, 25600};
  pk.a[9]  = {b_out, c_b_out, 50};
  pk.a[10] = {trans, c_trans, 2500};
  convert_kernel<<<dim3(512, 11), 256, 0, stream>>>(pk, pflag);

  embed_kernel<<<(T_ * B_) / 8, 256, 0, stream>>>(tokens, embed, pflag, xbuf);
  lstm_kernel<<<128, 256, 0, stream>>>(c_whh_f, c_wih_f, c_b_f,
                                       c_whh_b, c_wih_b, c_b_b,
                                       xbuf, hf, hb, flags);
  enc_kernel<<<dim3(256, 4), 256, 0, stream>>>(hf, hb, c_w_enc, c_b_enc, states);
  emit_kernel<<<256, 256, 0, stream>>>(states, c_w_out, c_b_out, emit);
  crf_kernel<<<16, 256, 0, stream>>>(emit, c_trans, pflag, d_out);
}

// Round 3
// 5776.826 us; speedup vs baseline: 1.1476x; 1.1476x over previous
//
#include <hip/hip_runtime.h>
#include <stdint.h>

#define T_ 512
#define B_ 64
#define E_ 256
#define H_ 512
#define KT 50

typedef __attribute__((ext_vector_type(8))) short bf16x8;
typedef __attribute__((ext_vector_type(4))) float f32x4;
typedef __attribute__((ext_vector_type(4))) int i32x4;

#define MFMA16(a,b,c) __builtin_amdgcn_mfma_f32_16x16x32_bf16((a),(b),(c),0,0,0)

static __device__ __forceinline__ float bf2f(unsigned short v) {
  unsigned int u = ((unsigned int)v) << 16; float f; __builtin_memcpy(&f, &u, 4); return f;
}
static __device__ __forceinline__ unsigned short f2bf(float f) {
  unsigned int u; __builtin_memcpy(&u, &f, 4);
  u += 0x7fffu + ((u >> 16) & 1u);
  return (unsigned short)(u >> 16);
}
static __device__ __forceinline__ float sigm(float x) { return 1.f / (1.f + __expf(-x)); }
static __device__ __forceinline__ float tanh_(float x) { return 2.f / (1.f + __expf(-2.f * x)) - 1.f; }

// ------------------------------------------------------------- dtype probe
__global__ void probe_kernel(const unsigned short* __restrict__ e,
                             unsigned int* __restrict__ flag) {
  int lane = threadIdx.x & 63;
  float a = fabsf(bf2f(e[2 * lane]));
  int good = (a >= 1e-8f && a <= 4.0f);
  unsigned long long m = __ballot(good);
  if (threadIdx.x == 0) flag[0] = (__popcll(m) >= 48) ? 1u : 0u;
}

// ------------------------------------------------------------- canonicalize
struct CvtArgs { const void* src; unsigned short* dst; int n; };
struct CvtPack { CvtArgs a[11]; };

__global__ __launch_bounds__(256) void convert_kernel(CvtPack p,
                                                      const unsigned int* __restrict__ flag) {
  CvtArgs c = p.a[blockIdx.y];
  int i = (blockIdx.x * 256 + threadIdx.x) * 8;
  if (i >= c.n) return;
  int isbf = *flag;
  if (i + 8 <= c.n) {
    if (isbf) {
      *(i32x4*)(c.dst + i) = *(const i32x4*)((const unsigned short*)c.src + i);
    } else {
      const float* s = (const float*)c.src;
      float4 a0 = *(const float4*)(s + i);
      float4 a1 = *(const float4*)(s + i + 4);
      unsigned short o[8] = {f2bf(a0.x), f2bf(a0.y), f2bf(a0.z), f2bf(a0.w),
                             f2bf(a1.x), f2bf(a1.y), f2bf(a1.z), f2bf(a1.w)};
      *(i32x4*)(c.dst + i) = *(i32x4*)o;
    }
  } else {
    for (int j = 0; j < 8; j++) {
      if (i + j < c.n) {
        c.dst[i + j] = isbf ? ((const unsigned short*)c.src)[i + j]
                            : f2bf(((const float*)c.src)[i + j]);
      }
    }
  }
}

// ---------------------------------------------------------------- embedding
__global__ __launch_bounds__(256) void embed_kernel(
    const int* __restrict__ tokens, const void* __restrict__ embed,
    const unsigned int* __restrict__ flag, unsigned short* __restrict__ x) {
  int tid = threadIdx.x;
  int row = blockIdx.x * 8 + (tid >> 5);   // row = t*64+b, 32768 rows
  int l = tid & 31;
  int tok = tokens[row];
  if (*flag) {
    const unsigned short* e = (const unsigned short*)embed;
    *(i32x4*)(x + (size_t)row * E_ + l * 8) =
        *(const i32x4*)(e + (size_t)tok * E_ + l * 8);
  } else {
    const float* e = (const float*)embed + (size_t)tok * E_ + l * 8;
    float4 a0 = *(const float4*)e;
    float4 a1 = *(const float4*)(e + 4);
    unsigned short o[8] = {f2bf(a0.x), f2bf(a0.y), f2bf(a0.z), f2bf(a0.w),
                           f2bf(a1.x), f2bf(a1.y), f2bf(a1.z), f2bf(a1.w)};
    *(i32x4*)(x + (size_t)row * E_ + l * 8) = *(i32x4*)o;
  }
}

// ---------------------------------------------------------------- BiLSTM
// 128 blocks; each WG owns 8 hidden units (32 gate rows). Weights pinned in
// VGPRs. Waves: each owns 4 h-K-chunks (128 K of H) + 2 x-K-chunks (64 of E).
// Per-step sync: producers atomicAdd a per-step counter after agent-scope h
// publish; consumers poll ONE address, then issue ALL h loads (batched, one
// logical RTT) before the MFMA chain.
__global__ __launch_bounds__(256) void lstm_kernel(
    const unsigned short* __restrict__ whh_f, const unsigned short* __restrict__ wih_f,
    const unsigned short* __restrict__ bias_f,
    const unsigned short* __restrict__ whh_b, const unsigned short* __restrict__ wih_b,
    const unsigned short* __restrict__ bias_b,
    const unsigned short* __restrict__ x,
    unsigned short* __restrict__ hf, unsigned short* __restrict__ hb,
    unsigned int* __restrict__ cnts) {
  const int tid = threadIdx.x;
  const int wv = tid >> 6, lane = tid & 63, q = lane >> 4, l15 = lane & 15;
  const int bid = blockIdx.x;
  const int dir = (bid >> 2) & 1;                 // (bid%8)<4 ? 0 : 1
  const int wg = (bid >> 3) * 4 + (bid & 3);      // 0..63 within direction
  const int u0 = wg * 8;

  const unsigned short* whh = dir ? whh_b : whh_f;
  const unsigned short* wih = dir ? wih_b : wih_f;
  const unsigned short* bvec = dir ? bias_b : bias_f;
  unsigned short* hbuf = dir ? hb : hf;
  unsigned int* cnt = cnts + (size_t)dir * T_;

  // ---- preload weight A-fragments (rows: [i0..7 f0..7] mt0, [g0..7 o0..7] mt1)
  // kl 0..3 -> h chunk kc = wv*4+kl (of 16); kl 4..5 -> x chunk ec = wv*2+(kl-4)
  bf16x8 afrag[2][6];
#pragma unroll
  for (int mt = 0; mt < 2; mt++) {
    int base = (mt == 0) ? ((l15 < 8) ? 0 : 512) : ((l15 < 8) ? 1024 : 1536);
    int row = base + u0 + (l15 & 7);
#pragma unroll
    for (int kl = 0; kl < 6; kl++) {
      const unsigned short* p = (kl < 4)
          ? (whh + (size_t)row * H_ + (wv * 4 + kl) * 32 + q * 8)
          : (wih + (size_t)row * E_ + (wv * 2 + (kl - 4)) * 32 + q * 8);
      afrag[mt][kl] = *(const bf16x8*)p;
    }
  }

  const int eb = tid & 63;
  const int uu = tid >> 6;
  float bg[2][4];
#pragma unroll
  for (int s = 0; s < 2; s++) {
    int u = uu + 4 * s;
#pragma unroll
    for (int g = 0; g < 4; g++) bg[s][g] = bf2f(bvec[g * H_ + u0 + u]);
  }
  float cst[2] = {0.f, 0.f};

  __shared__ float pacc[4][32][66];
  __shared__ __align__(16) unsigned short h_out[64][8];

  for (int step = 0; step < T_; step++) {
    const int t = dir ? (T_ - 1 - step) : step;
    f32x4 acc0[4], acc1[4];
#pragma unroll
    for (int nt = 0; nt < 4; nt++) {
      acc0[nt] = (f32x4){0.f, 0.f, 0.f, 0.f};
      acc1[nt] = (f32x4){0.f, 0.f, 0.f, 0.f};
    }

    // x-part (independent of h — overlaps producer latency)
    {
      const unsigned short* xb = x + (size_t)t * B_ * E_;
#pragma unroll
      for (int kl = 4; kl < 6; kl++) {
        int ec = wv * 2 + (kl - 4);
#pragma unroll
        for (int nt = 0; nt < 4; nt++) {
          int b = nt * 16 + l15;
          bf16x8 bx = *(const bf16x8*)(xb + (size_t)b * E_ + ec * 32 + q * 8);
          acc0[nt] = MFMA16(afrag[0][kl], bx, acc0[nt]);
          acc1[nt] = MFMA16(afrag[1][kl], bx, acc1[nt]);
        }
      }
    }

    if (step > 0) {
      // wait for all 64 producer WGs of this direction (single-address poll)
      for (;;) {
        unsigned int c = __hip_atomic_load(cnt + step - 1, __ATOMIC_RELAXED,
                                           __HIP_MEMORY_SCOPE_AGENT);
        if (__builtin_amdgcn_readfirstlane(c) >= 64) break;
        __builtin_amdgcn_s_sleep(2);
      }
      asm volatile("" ::: "memory");  // no hoisting of h loads above the wait

      const int tprev = dir ? (t + 1) : (t - 1);
      const unsigned int* h32 = (const unsigned int*)(hbuf + (size_t)tprev * B_ * H_);

      // batched coherent gather: all 64 dword loads in flight before use
      unsigned int hr[4][4][4];
#pragma unroll
      for (int kl = 0; kl < 4; kl++) {
        int kc = wv * 4 + kl;
#pragma unroll
        for (int nt = 0; nt < 4; nt++) {
          int b = nt * 16 + l15;
          const unsigned int* p = h32 + b * (H_ / 2) + kc * 16 + q * 4;
#pragma unroll
          for (int d = 0; d < 4; d++)
            hr[kl][nt][d] = __hip_atomic_load(p + d, __ATOMIC_RELAXED,
                                              __HIP_MEMORY_SCOPE_AGENT);
        }
      }
#pragma unroll
      for (int kl = 0; kl < 4; kl++) {
#pragma unroll
        for (int nt = 0; nt < 4; nt++) {
          bf16x8 bh;
          __builtin_memcpy(&bh, hr[kl][nt], 16);
          acc0[nt] = MFMA16(afrag[0][kl], bh, acc0[nt]);
          acc1[nt] = MFMA16(afrag[1][kl], bh, acc1[nt]);
        }
      }
    }

    __syncthreads();
#pragma unroll
    for (int nt = 0; nt < 4; nt++) {
      int b = nt * 16 + l15;
#pragma unroll
      for (int r = 0; r < 4; r++) {
        pacc[wv][q * 4 + r][b] = acc0[nt][r];
        pacc[wv][16 + q * 4 + r][b] = acc1[nt][r];
      }
    }
    __syncthreads();

#pragma unroll
    for (int s = 0; s < 2; s++) {
      int u = uu + 4 * s;
      float gi = bg[s][0], gf = bg[s][1], gg = bg[s][2], go = bg[s][3];
#pragma unroll
      for (int w = 0; w < 4; w++) {
        gi += pacc[w][u][eb];
        gf += pacc[w][8 + u][eb];
        gg += pacc[w][16 + u][eb];
        go += pacc[w][24 + u][eb];
      }
      float cn = sigm(gf) * cst[s] + sigm(gi) * tanh_(gg);
      cst[s] = cn;
      float h = sigm(go) * tanh_(cn);
      h_out[eb][u] = f2bf(h);
    }
    __syncthreads();

    if (wv == 0) {  // publish h slice (agent scope) then bump arrival counter
      const unsigned int* hw = (const unsigned int*)&h_out[lane][0];
      unsigned int* gp = (unsigned int*)(hbuf + ((size_t)t * B_ + lane) * H_ + u0);
#pragma unroll
      for (int i = 0; i < 4; i++)
        __hip_atomic_store(gp + i, hw[i], __ATOMIC_RELAXED, __HIP_MEMORY_SCOPE_AGENT);
      asm volatile("s_waitcnt vmcnt(0)" ::: "memory");
      if (lane == 0)
        __hip_atomic_fetch_add(cnt + step, 1u, __ATOMIC_RELAXED,
                               __HIP_MEMORY_SCOPE_AGENT);
    }
  }
}

// ---------------------------------------------------------------- encoder GEMM
// states = tanh([hf|hb] @ w_enc^T + b_enc): M=32768, K=1024, N=512
__global__ __launch_bounds__(256) void enc_kernel(
    const unsigned short* __restrict__ hf, const unsigned short* __restrict__ hb,
    const unsigned short* __restrict__ w_enc, const unsigned short* __restrict__ b_enc,
    unsigned short* __restrict__ states) {
  const int tid = threadIdx.x;
  const int bm = blockIdx.x, bn = blockIdx.y;
  const int wv = tid >> 6, lane = tid & 63, q = lane >> 4, l15 = lane & 15;
  const int wm = wv >> 1, wn = wv & 1;

  __shared__ __align__(16) unsigned short a_lds[128][72];
  __shared__ __align__(16) unsigned short b_lds[128][72];
  __shared__ __align__(16) unsigned short st_lds[128][136];

  f32x4 acc[4][4];
#pragma unroll
  for (int mt = 0; mt < 4; mt++)
#pragma unroll
    for (int nt = 0; nt < 4; nt++) acc[mt][nt] = (f32x4){0.f, 0.f, 0.f, 0.f};

  for (int c = 0; c < 16; c++) {
    const unsigned short* asrc = (c < 8) ? hf : hb;
    int kof = (c & 7) * 64;
#pragma unroll
    for (int p = 0; p < 4; p++) {
      int u = tid + p * 256;
      int r = u >> 3, wu = u & 7;
      *(i32x4*)&a_lds[r][wu * 8] =
          *(const i32x4*)(asrc + (size_t)(bm * 128 + r) * H_ + kof + wu * 8);
      *(i32x4*)&b_lds[r][wu * 8] =
          *(const i32x4*)(w_enc + (size_t)(bn * 128 + r) * 1024 + c * 64 + wu * 8);
    }
    __syncthreads();
#pragma unroll
    for (int kk = 0; kk < 64; kk += 32) {
      bf16x8 af[4], bfr[4];
#pragma unroll
      for (int mt = 0; mt < 4; mt++)
        af[mt] = *(const bf16x8*)&a_lds[wm * 64 + mt * 16 + l15][kk + q * 8];
#pragma unroll
      for (int nt = 0; nt < 4; nt++)
        bfr[nt] = *(const bf16x8*)&b_lds[wn * 64 + nt * 16 + l15][kk + q * 8];
#pragma unroll
      for (int mt = 0; mt < 4; mt++)
#pragma unroll
        for (int nt = 0; nt < 4; nt++) acc[mt][nt] = MFMA16(af[mt], bfr[nt], acc[mt][nt]);
    }
    __syncthreads();
  }

  float be[4];
#pragma unroll
  for (int nt = 0; nt < 4; nt++)
    be[nt] = bf2f(b_enc[bn * 128 + wn * 64 + nt * 16 + l15]);
#pragma unroll
  for (int mt = 0; mt < 4; mt++)
#pragma unroll
    for (int nt = 0; nt < 4; nt++)
#pragma unroll
      for (int r = 0; r < 4; r++) {
        float v = tanh_(acc[mt][nt][r] + be[nt]);
        st_lds[wm * 64 + mt * 16 + q * 4 + r][wn * 64 + nt * 16 + l15] = f2bf(v);
      }
  __syncthreads();
#pragma unroll
  for (int p = 0; p < 8; p++) {
    int u = tid + p * 256;
    int r = u >> 4, w = u & 15;
    *(i32x4*)(states + (size_t)(bm * 128 + r) * H_ + bn * 128 + w * 8) =
        *(const i32x4*)&st_lds[r][w * 8];
  }
}

// ---------------------------------------------------------------- emit GEMM
// emit = states @ w_out^T + b_out: M=32768, K=512, N=50 (padded 64), fp32 out
__global__ __launch_bounds__(256) void emit_kernel(
    const unsigned short* __restrict__ states, const unsigned short* __restrict__ w_out,
    const unsigned short* __restrict__ b_out, float* __restrict__ emit) {
  const int tid = threadIdx.x;
  const int bm = blockIdx.x;
  const int wv = tid >> 6, lane = tid & 63, q = lane >> 4, l15 = lane & 15;
  const int wm = wv >> 1, wn = wv & 1;

  __shared__ __align__(16) unsigned short wo_lds[64][520];
  __shared__ __align__(16) unsigned short a_lds[128][72];

#pragma unroll
  for (int p = 0; p < 16; p++) {
    int u = tid + p * 256;
    int r = u >> 6, wu = u & 63;
    i32x4 v = {0, 0, 0, 0};
    if (r < KT) v = *(const i32x4*)(w_out + (size_t)r * H_ + wu * 8);
    *(i32x4*)&wo_lds[r][wu * 8] = v;
  }

  f32x4 acc[4][2];
#pragma unroll
  for (int mt = 0; mt < 4; mt++)
#pragma unroll
    for (int nt = 0; nt < 2; nt++) acc[mt][nt] = (f32x4){0.f, 0.f, 0.f, 0.f};

  for (int c = 0; c < 8; c++) {
    __syncthreads();
#pragma unroll
    for (int p = 0; p < 4; p++) {
      int u = tid + p * 256;
      int r = u >> 3, wu = u & 7;
      *(i32x4*)&a_lds[r][wu * 8] =
          *(const i32x4*)(states + (size_t)(bm * 128 + r) * H_ + c * 64 + wu * 8);
    }
    __syncthreads();
#pragma unroll
    for (int kk = 0; kk < 64; kk += 32) {
      bf16x8 af[4], bfr[2];
#pragma unroll
      for (int mt = 0; mt < 4; mt++)
        af[mt] = *(const bf16x8*)&a_lds[wm * 64 + mt * 16 + l15][kk + q * 8];
#pragma unroll
      for (int nt = 0; nt < 2; nt++)
        bfr[nt] = *(const bf16x8*)&wo_lds[wn * 32 + nt * 16 + l15][c * 64 + kk + q * 8];
#pragma unroll
      for (int mt = 0; mt < 4; mt++)
#pragma unroll
        for (int nt = 0; nt < 2; nt++) acc[mt][nt] = MFMA16(af[mt], bfr[nt], acc[mt][nt]);
    }
  }

  float bo[2];
#pragma unroll
  for (int nt = 0; nt < 2; nt++) {
    int n = wn * 32 + nt * 16 + l15;
    bo[nt] = (n < KT) ? bf2f(b_out[n]) : 0.f;
  }
#pragma unroll
  for (int mt = 0; mt < 4; mt++)
#pragma unroll
    for (int nt = 0; nt < 2; nt++) {
      int n = wn * 32 + nt * 16 + l15;
      if (n < KT) {
#pragma unroll
        for (int r = 0; r < 4; r++) {
          int m = bm * 128 + wm * 64 + mt * 16 + q * 4 + r;
          emit[(size_t)m * KT + n] = acc[mt][nt][r] + bo[nt];
        }
      }
    }
}

// ---------------------------------------------------------------- CRF forward
__global__ __launch_bounds__(256) void crf_kernel(
    const float* __restrict__ emit, const unsigned short* __restrict__ trans,
    const unsigned int* __restrict__ flag, void* __restrict__ out) {
  const int tid = threadIdx.x;
  const int wv = tid >> 6, lane = tid & 63;
  const int b = blockIdx.x * 4 + wv;
  const int jj = (lane < KT) ? lane : (KT - 1);

  float tr[KT];
  float mj = -1e30f;
#pragma unroll
  for (int i = 0; i < KT; i++) {
    tr[i] = bf2f(trans[jj * KT + i]);
    mj = fmaxf(mj, tr[i]);
  }
  float et[KT];
#pragma unroll
  for (int i = 0; i < KT; i++) et[i] = __expf(tr[i] - mj);
  float tr_stop = bf2f(trans[(KT - 1) * KT + jj]);

  float alpha = (lane == 0) ? 0.f : -1e30f;
  float e_next = emit[(size_t)b * KT + jj];

  for (int t = 0; t < T_; t++) {
    float e_cur = e_next;
    if (t < T_ - 1) e_next = emit[((size_t)(t + 1) * B_ + b) * KT + jj];
    float M = alpha;
#pragma unroll
    for (int off = 32; off; off >>= 1) M = fmaxf(M, __shfl_xor(M, off, 64));
    float p = __expf(alpha - M);
    float s = 0.f;
#pragma unroll
    for (int i = 0; i < KT; i++) {
      float pi = __uint_as_float(__builtin_amdgcn_readlane(__float_as_uint(p), i));
      s = __builtin_fmaf(et[i], pi, s);
    }
    float an = e_cur + mj + M + __logf(s);
    alpha = (lane < KT) ? an : -1e30f;
  }

  float v = (lane < KT) ? (alpha + tr_stop) : -1e30f;
  float M2 = v;
#pragma unroll
  for (int off = 32; off; off >>= 1) M2 = fmaxf(M2, __shfl_xor(M2, off, 64));
  float s2 = (lane < KT) ? __expf(v - M2) : 0.f;
#pragma unroll
  for (int off = 32; off; off >>= 1) s2 += __shfl_xor(s2, off, 64);
  float lz = M2 + __logf(s2);
  if (lane == 0) {
    if (*flag) ((unsigned short*)out)[b] = f2bf(lz);
    else ((float*)out)[b] = lz;
  }
}

// ---------------------------------------------------------------- launch
extern "C" void kernel_launch(void* const* d_in, const int* in_sizes, int n_in,
                              void* d_out, int out_size, void* d_ws, size_t ws_size,
                              hipStream_t stream) {
  const int* tokens = (const int*)d_in[0];
  const void* embed = d_in[1];
  const void* wih_f = d_in[2];
  const void* whh_f = d_in[3];
  const void* b_f = d_in[4];
  const void* wih_b = d_in[5];
  const void* whh_b = d_in[6];
  const void* b_b = d_in[7];
  const void* w_enc = d_in[8];
  const void* b_enc = d_in[9];
  const void* w_out = d_in[10];
  const void* b_out = d_in[11];
  const void* trans = d_in[12];

  char* ws = (char*)d_ws;
  unsigned int* cnts = (unsigned int*)ws;                        // 4096 B used
  unsigned int* pflag = (unsigned int*)(ws + 262144);            // 256 B
  unsigned short* xbuf = (unsigned short*)(ws + 262400);         // 16 MB
  unsigned short* hf = (unsigned short*)(ws + 17039616);         // 32 MB
  unsigned short* hb = (unsigned short*)(ws + 50594048);         // 32 MB
  unsigned short* states = (unsigned short*)(ws + 84148480);     // 32 MB
  float* emit = (float*)(ws + 117702912);                        // 6.55 MB
  unsigned short* canon = (unsigned short*)(ws + 124256512);     // 7.4 MB

  unsigned short* c_wih_f = canon + 0;
  unsigned short* c_whh_f = canon + 524288;
  unsigned short* c_b_f   = canon + 1572864;
  unsigned short* c_wih_b = canon + 1574912;
  unsigned short* c_whh_b = canon + 2099200;
  unsigned short* c_b_b   = canon + 3147776;
  unsigned short* c_w_enc = canon + 3149824;
  unsigned short* c_b_enc = canon + 3674112;
  unsigned short* c_w_out = canon + 3674624;
  unsigned short* c_b_out = canon + 3700224;
  unsigned short* c_trans = canon + 3700352;

  hipMemsetAsync(cnts, 0, 2 * T_ * sizeof(unsigned int), stream);
  probe_kernel<<<1, 64, 0, stream>>>((const unsigned short*)embed, pflag);

  CvtPack pk;
  pk.a[0]  = {wih_f, c_wih_f, 524288};
  pk.a[1]  = {whh_f, c_whh_f, 1048576};
  pk.a[2]  = {b_f,   c_b_f,   2048};
  pk.a[3]  = {wih_b, c_wih_b, 524288};
  pk.a[4]  = {whh_b, c_whh_b, 1048576};
  pk.a[5]  = {b_b,   c_b_b,   2048};
  pk.a[6]  = {w_enc, c_w_enc, 524288};
  pk.a[7]  = {b_enc, c_b_enc, 512};
  pk.a[8]  = {w_out, c_w_out, 25600};
  pk.a[9]  = {b_out, c_b_out, 50};
  pk.a[10] = {trans, c_trans, 2500};
  convert_kernel<<<dim3(512, 11), 256, 0, stream>>>(pk, pflag);

  embed_kernel<<<(T_ * B_) / 8, 256, 0, stream>>>(tokens, embed, pflag, xbuf);
  lstm_kernel<<<128, 256, 0, stream>>>(c_whh_f, c_wih_f, c_b_f,
                                       c_whh_b, c_wih_b, c_b_b,
                                       xbuf, hf, hb, cnts);
  enc_kernel<<<dim3(256, 4), 256, 0, stream>>>(hf, hb, c_w_enc, c_b_enc, states);
  emit_kernel<<<256, 256, 0, stream>>>(states, c_w_out, c_b_out, emit);
  crf_kernel<<<16, 256, 0, stream>>>(emit, c_trans, pflag, d_out);
}

// Round 4
// 4094.633 us; speedup vs baseline: 1.6190x; 1.4108x over previous
//
#include <hip/hip_runtime.h>
#include <stdint.h>

#define T_ 512
#define B_ 64
#define E_ 256
#define H_ 512
#define KT 50

typedef __attribute__((ext_vector_type(8))) short bf16x8;
typedef __attribute__((ext_vector_type(4))) float f32x4;
typedef __attribute__((ext_vector_type(4))) int i32x4;

#define MFMA16(a,b,c) __builtin_amdgcn_mfma_f32_16x16x32_bf16((a),(b),(c),0,0,0)

static __device__ __forceinline__ float bf2f(unsigned short v) {
  unsigned int u = ((unsigned int)v) << 16; float f; __builtin_memcpy(&f, &u, 4); return f;
}
static __device__ __forceinline__ unsigned short f2bf(float f) {
  unsigned int u; __builtin_memcpy(&u, &f, 4);
  u += 0x7fffu + ((u >> 16) & 1u);
  return (unsigned short)(u >> 16);
}
static __device__ __forceinline__ float sigm(float x) { return 1.f / (1.f + __expf(-x)); }
static __device__ __forceinline__ float tanh_(float x) { return 2.f / (1.f + __expf(-2.f * x)) - 1.f; }

// ------------------------------------------------------------- dtype probe
__global__ void probe_kernel(const unsigned short* __restrict__ e,
                             unsigned int* __restrict__ flag) {
  int lane = threadIdx.x & 63;
  float a = fabsf(bf2f(e[2 * lane]));
  int good = (a >= 1e-8f && a <= 4.0f);
  unsigned long long m = __ballot(good);
  if (threadIdx.x == 0) flag[0] = (__popcll(m) >= 48) ? 1u : 0u;
}

// ------------------------------------------------------------- canonicalize
struct CvtArgs { const void* src; unsigned short* dst; int n; };
struct CvtPack { CvtArgs a[11]; };

__global__ __launch_bounds__(256) void convert_kernel(CvtPack p,
                                                      const unsigned int* __restrict__ flag) {
  CvtArgs c = p.a[blockIdx.y];
  int i = (blockIdx.x * 256 + threadIdx.x) * 8;
  if (i >= c.n) return;
  int isbf = *flag;
  if (i + 8 <= c.n) {
    if (isbf) {
      *(i32x4*)(c.dst + i) = *(const i32x4*)((const unsigned short*)c.src + i);
    } else {
      const float* s = (const float*)c.src;
      float4 a0 = *(const float4*)(s + i);
      float4 a1 = *(const float4*)(s + i + 4);
      unsigned short o[8] = {f2bf(a0.x), f2bf(a0.y), f2bf(a0.z), f2bf(a0.w),
                             f2bf(a1.x), f2bf(a1.y), f2bf(a1.z), f2bf(a1.w)};
      *(i32x4*)(c.dst + i) = *(i32x4*)o;
    }
  } else {
    for (int j = 0; j < 8; j++) {
      if (i + j < c.n) {
        c.dst[i + j] = isbf ? ((const unsigned short*)c.src)[i + j]
                            : f2bf(((const float*)c.src)[i + j]);
      }
    }
  }
}

// ---------------------------------------------------------------- embedding
__global__ __launch_bounds__(256) void embed_kernel(
    const int* __restrict__ tokens, const void* __restrict__ embed,
    const unsigned int* __restrict__ flag, unsigned short* __restrict__ x) {
  int tid = threadIdx.x;
  int row = blockIdx.x * 8 + (tid >> 5);   // row = t*64+b, 32768 rows
  int l = tid & 31;
  int tok = tokens[row];
  if (*flag) {
    const unsigned short* e = (const unsigned short*)embed;
    *(i32x4*)(x + (size_t)row * E_ + l * 8) =
        *(const i32x4*)(e + (size_t)tok * E_ + l * 8);
  } else {
    const float* e = (const float*)embed + (size_t)tok * E_ + l * 8;
    float4 a0 = *(const float4*)e;
    float4 a1 = *(const float4*)(e + 4);
    unsigned short o[8] = {f2bf(a0.x), f2bf(a0.y), f2bf(a0.z), f2bf(a0.w),
                           f2bf(a1.x), f2bf(a1.y), f2bf(a1.z), f2bf(a1.w)};
    *(i32x4*)(x + (size_t)row * E_ + l * 8) = *(i32x4*)o;
  }
}

// ---------------------------------------------------------------- BiLSTM
// 64 blocks: dir = bid&1, wg = bid>>1 (32 WGs/dir, 16 units each = 64 gate
// rows). Weights pinned in VGPRs (24 A-frags/wave). h stored FRAGMENT-NATIVE:
// dword index = t*16384 + (u>>3)*256 + b*4 + j2  (slab u>>3 == kc*4+q), so
// both producer publish and consumer B-frag gather are lane-coalesced.
// Sync: producers atomicAdd into 8 line-separated buckets; ONE poller wave
// per WG polls (8 lanes, 1 instr), then releases siblings via LDS go-word.
__global__ __launch_bounds__(256, 1) void lstm_kernel(
    const unsigned short* __restrict__ whh_f, const unsigned short* __restrict__ wih_f,
    const unsigned short* __restrict__ bias_f,
    const unsigned short* __restrict__ whh_b, const unsigned short* __restrict__ wih_b,
    const unsigned short* __restrict__ bias_b,
    const unsigned short* __restrict__ x,
    unsigned short* __restrict__ hf, unsigned short* __restrict__ hb,
    unsigned int* __restrict__ cnts) {
  const int tid = threadIdx.x;
  const int wv = tid >> 6, lane = tid & 63, q = lane >> 4, l15 = lane & 15;
  const int bid = blockIdx.x;
  const int dir = bid & 1;
  const int wg = bid >> 1;            // 0..31 within direction
  const int u0 = wg * 16;

  const unsigned short* whh = dir ? whh_b : whh_f;
  const unsigned short* wih = dir ? wih_b : wih_f;
  const unsigned short* bvec = dir ? bias_b : bias_f;
  unsigned short* hbuf = dir ? hb : hf;
  // counters: bucket-major, bucket stride 1024 dwords (4 KB, line-separated)
  unsigned int* cbase = cnts + (size_t)dir * T_;

  // ---- preload weight A-fragments: afrag[gate mt][k-chunk kl]
  // rows: gate mt, unit u0+l15; kl 0..3 -> h-chunk wv*4+kl; kl 4..5 -> x-chunk
  bf16x8 afrag[4][6];
#pragma unroll
  for (int mt = 0; mt < 4; mt++) {
    int row = mt * H_ + u0 + l15;
#pragma unroll
    for (int kl = 0; kl < 6; kl++) {
      const unsigned short* p = (kl < 4)
          ? (whh + (size_t)row * H_ + (wv * 4 + kl) * 32 + q * 8)
          : (wih + (size_t)row * E_ + (wv * 2 + (kl - 4)) * 32 + q * 8);
      afrag[mt][kl] = *(const bf16x8*)p;
    }
  }

  // elementwise mapping: thread owns b = tid&63, units uu+4s (s=0..3)
  const int eb = tid & 63;
  const int uu = tid >> 6;
  float bg[4][4];
#pragma unroll
  for (int s = 0; s < 4; s++) {
    int u = uu + 4 * s;
#pragma unroll
    for (int g = 0; g < 4; g++) bg[s][g] = bf2f(bvec[g * H_ + u0 + u]);
  }
  float cst[4] = {0.f, 0.f, 0.f, 0.f};

  __shared__ float pacc[4][64][66];
  __shared__ __align__(16) unsigned short h_out[64][16];
  __shared__ unsigned int go_word;
  if (tid == 0) go_word = 0;

  for (int step = 0; step < T_; step++) {
    const int t = dir ? (T_ - 1 - step) : step;
    f32x4 acc[4][4];
#pragma unroll
    for (int mt = 0; mt < 4; mt++)
#pragma unroll
      for (int nt = 0; nt < 4; nt++) acc[mt][nt] = (f32x4){0.f, 0.f, 0.f, 0.f};

    // x-part (independent of h — overlaps producer latency)
    {
      const unsigned short* xb = x + (size_t)t * B_ * E_;
#pragma unroll
      for (int kl = 4; kl < 6; kl++) {
        int ec = wv * 2 + (kl - 4);
#pragma unroll
        for (int nt = 0; nt < 4; nt++) {
          int b = nt * 16 + l15;
          bf16x8 bx = *(const bf16x8*)(xb + (size_t)b * E_ + ec * 32 + q * 8);
#pragma unroll
          for (int mt = 0; mt < 4; mt++)
            acc[mt][nt] = MFMA16(afrag[mt][kl], bx, acc[mt][nt]);
        }
      }
    }

    if (step > 0) {
      if (wv == 1) {  // designated poller: 8 buckets in one instruction
        unsigned int* cp = cbase + (size_t)(lane & 7) * 1024 + (step - 1);
        for (;;) {
          unsigned int v = __hip_atomic_load(cp, __ATOMIC_RELAXED,
                                             __HIP_MEMORY_SCOPE_AGENT);
          int sv = (lane < 8) ? (int)v : 0;
          sv += __shfl_xor(sv, 1);
          sv += __shfl_xor(sv, 2);
          sv += __shfl_xor(sv, 4);
          if (__builtin_amdgcn_readfirstlane(sv) >= 32) break;
          __builtin_amdgcn_s_sleep(4);
        }
        __hip_atomic_store(&go_word, (unsigned int)step, __ATOMIC_RELAXED,
                           __HIP_MEMORY_SCOPE_WORKGROUP);
      } else {        // siblings spin on LDS (no fabric traffic)
        while (__hip_atomic_load(&go_word, __ATOMIC_RELAXED,
                                 __HIP_MEMORY_SCOPE_WORKGROUP) < (unsigned int)step)
          __builtin_amdgcn_s_sleep(1);
      }
      asm volatile("" ::: "memory");  // no hoisting of h loads above the wait

      const int tprev = dir ? (t + 1) : (t - 1);
      const unsigned int* hD = (const unsigned int*)hbuf + (size_t)tprev * 16384;

      // coalesced batched gather: 64 dword atomic loads, all in flight
      unsigned int hr[4][4][4];
#pragma unroll
      for (int kl = 0; kl < 4; kl++) {
        unsigned int* sb = (unsigned int*)hD + ((wv * 4 + kl) * 4 + q) * 256;
#pragma unroll
        for (int nt = 0; nt < 4; nt++) {
          unsigned int* p = sb + (nt * 16 + l15) * 4;
#pragma unroll
          for (int d = 0; d < 4; d++)
            hr[kl][nt][d] = __hip_atomic_load(p + d, __ATOMIC_RELAXED,
                                              __HIP_MEMORY_SCOPE_AGENT);
        }
      }
#pragma unroll
      for (int kl = 0; kl < 4; kl++) {
#pragma unroll
        for (int nt = 0; nt < 4; nt++) {
          bf16x8 bh;
          __builtin_memcpy(&bh, hr[kl][nt], 16);
#pragma unroll
          for (int mt = 0; mt < 4; mt++)
            acc[mt][nt] = MFMA16(afrag[mt][kl], bh, acc[mt][nt]);
        }
      }
    }

    __syncthreads();
#pragma unroll
    for (int mt = 0; mt < 4; mt++)
#pragma unroll
      for (int nt = 0; nt < 4; nt++)
#pragma unroll
        for (int r = 0; r < 4; r++)
          pacc[wv][mt * 16 + q * 4 + r][nt * 16 + l15] = acc[mt][nt][r];
    __syncthreads();

#pragma unroll
    for (int s = 0; s < 4; s++) {
      int u = uu + 4 * s;
      float gi = bg[s][0], gf = bg[s][1], gg = bg[s][2], og = bg[s][3];
#pragma unroll
      for (int w = 0; w < 4; w++) {
        gi += pacc[w][u][eb];
        gf += pacc[w][16 + u][eb];
        gg += pacc[w][32 + u][eb];
        og += pacc[w][48 + u][eb];
      }
      float cn = sigm(gf) * cst[s] + sigm(gi) * tanh_(gg);
      cst[s] = cn;
      h_out[eb][u] = f2bf(sigm(og) * tanh_(cn));
    }
    __syncthreads();

    if (wv == 0) {  // coalesced publish (2 slabs of 4 dwords/lane) + bucket add
      const unsigned int* hw = (const unsigned int*)&h_out[lane][0];
      unsigned int* gp = (unsigned int*)hbuf + (size_t)t * 16384 + wg * 512 + lane * 4;
#pragma unroll
      for (int i = 0; i < 4; i++)
        __hip_atomic_store(gp + i, hw[i], __ATOMIC_RELAXED, __HIP_MEMORY_SCOPE_AGENT);
#pragma unroll
      for (int i = 0; i < 4; i++)
        __hip_atomic_store(gp + 256 + i, hw[4 + i], __ATOMIC_RELAXED,
                           __HIP_MEMORY_SCOPE_AGENT);
      asm volatile("s_waitcnt vmcnt(0)" ::: "memory");
      if (lane == 0)
        __hip_atomic_fetch_add(cbase + (size_t)(wg & 7) * 1024 + step, 1u,
                               __ATOMIC_RELAXED, __HIP_MEMORY_SCOPE_AGENT);
    }
  }
}

// ---------------------------------------------------------------- encoder GEMM
// states = tanh([hf|hb] @ w_enc^T + b_enc): M=32768, K=1024, N=512.
// hf/hb are in fragment-native layout: dword = t*16384 + (u>>3)*256 + b*4 + j2
__global__ __launch_bounds__(256) void enc_kernel(
    const unsigned short* __restrict__ hf, const unsigned short* __restrict__ hb,
    const unsigned short* __restrict__ w_enc, const unsigned short* __restrict__ b_enc,
    unsigned short* __restrict__ states) {
  const int tid = threadIdx.x;
  const int bm = blockIdx.x, bn = blockIdx.y;
  const int wv = tid >> 6, lane = tid & 63, q = lane >> 4, l15 = lane & 15;
  const int wm = wv >> 1, wn = wv & 1;

  __shared__ __align__(16) unsigned short a_lds[128][72];
  __shared__ __align__(16) unsigned short b_lds[128][72];
  __shared__ __align__(16) unsigned short st_lds[128][136];

  f32x4 acc[4][4];
#pragma unroll
  for (int mt = 0; mt < 4; mt++)
#pragma unroll
    for (int nt = 0; nt < 4; nt++) acc[mt][nt] = (f32x4){0.f, 0.f, 0.f, 0.f};

  for (int c = 0; c < 16; c++) {
    const unsigned short* asrc = (c < 8) ? hf : hb;
    int kof = (c & 7) * 64;
#pragma unroll
    for (int p = 0; p < 4; p++) {
      int u_ = tid + p * 256;
      int r = u_ >> 3, wu = u_ & 7;
      int grow = bm * 128 + r;   // t = grow>>6, b = grow&63
      *(i32x4*)&a_lds[r][wu * 8] =
          *(const i32x4*)((const unsigned int*)asrc + (size_t)(grow >> 6) * 16384 +
                          (size_t)((kof >> 3) + wu) * 256 + (grow & 63) * 4);
      *(i32x4*)&b_lds[r][wu * 8] =
          *(const i32x4*)(w_enc + (size_t)(bn * 128 + r) * 1024 + c * 64 + wu * 8);
    }
    __syncthreads();
#pragma unroll
    for (int kk = 0; kk < 64; kk += 32) {
      bf16x8 af[4], bfr[4];
#pragma unroll
      for (int mt = 0; mt < 4; mt++)
        af[mt] = *(const bf16x8*)&a_lds[wm * 64 + mt * 16 + l15][kk + q * 8];
#pragma unroll
      for (int nt = 0; nt < 4; nt++)
        bfr[nt] = *(const bf16x8*)&b_lds[wn * 64 + nt * 16 + l15][kk + q * 8];
#pragma unroll
      for (int mt = 0; mt < 4; mt++)
#pragma unroll
        for (int nt = 0; nt < 4; nt++) acc[mt][nt] = MFMA16(af[mt], bfr[nt], acc[mt][nt]);
    }
    __syncthreads();
  }

  float be[4];
#pragma unroll
  for (int nt = 0; nt < 4; nt++)
    be[nt] = bf2f(b_enc[bn * 128 + wn * 64 + nt * 16 + l15]);
#pragma unroll
  for (int mt = 0; mt < 4; mt++)
#pragma unroll
    for (int nt = 0; nt < 4; nt++)
#pragma unroll
      for (int r = 0; r < 4; r++) {
        float v = tanh_(acc[mt][nt][r] + be[nt]);
        st_lds[wm * 64 + mt * 16 + q * 4 + r][wn * 64 + nt * 16 + l15] = f2bf(v);
      }
  __syncthreads();
#pragma unroll
  for (int p = 0; p < 8; p++) {
    int u_ = tid + p * 256;
    int r = u_ >> 4, w = u_ & 15;
    *(i32x4*)(states + (size_t)(bm * 128 + r) * H_ + bn * 128 + w * 8) =
        *(const i32x4*)&st_lds[r][w * 8];
  }
}

// ---------------------------------------------------------------- emit GEMM
// emit = states @ w_out^T + b_out: M=32768, K=512, N=50 (padded 64), fp32 out
__global__ __launch_bounds__(256) void emit_kernel(
    const unsigned short* __restrict__ states, const unsigned short* __restrict__ w_out,
    const unsigned short* __restrict__ b_out, float* __restrict__ emit) {
  const int tid = threadIdx.x;
  const int bm = blockIdx.x;
  const int wv = tid >> 6, lane = tid & 63, q = lane >> 4, l15 = lane & 15;
  const int wm = wv >> 1, wn = wv & 1;

  __shared__ __align__(16) unsigned short wo_lds[64][520];
  __shared__ __align__(16) unsigned short a_lds[128][72];

#pragma unroll
  for (int p = 0; p < 16; p++) {
    int u = tid + p * 256;
    int r = u >> 6, wu = u & 63;
    i32x4 v = {0, 0, 0, 0};
    if (r < KT) v = *(const i32x4*)(w_out + (size_t)r * H_ + wu * 8);
    *(i32x4*)&wo_lds[r][wu * 8] = v;
  }

  f32x4 acc[4][2];
#pragma unroll
  for (int mt = 0; mt < 4; mt++)
#pragma unroll
    for (int nt = 0; nt < 2; nt++) acc[mt][nt] = (f32x4){0.f, 0.f, 0.f, 0.f};

  for (int c = 0; c < 8; c++) {
    __syncthreads();
#pragma unroll
    for (int p = 0; p < 4; p++) {
      int u = tid + p * 256;
      int r = u >> 3, wu = u & 7;
      *(i32x4*)&a_lds[r][wu * 8] =
          *(const i32x4*)(states + (size_t)(bm * 128 + r) * H_ + c * 64 + wu * 8);
    }
    __syncthreads();
#pragma unroll
    for (int kk = 0; kk < 64; kk += 32) {
      bf16x8 af[4], bfr[2];
#pragma unroll
      for (int mt = 0; mt < 4; mt++)
        af[mt] = *(const bf16x8*)&a_lds[wm * 64 + mt * 16 + l15][kk + q * 8];
#pragma unroll
      for (int nt = 0; nt < 2; nt++)
        bfr[nt] = *(const bf16x8*)&wo_lds[wn * 32 + nt * 16 + l15][c * 64 + kk + q * 8];
#pragma unroll
      for (int mt = 0; mt < 4; mt++)
#pragma unroll
        for (int nt = 0; nt < 2; nt++) acc[mt][nt] = MFMA16(af[mt], bfr[nt], acc[mt][nt]);
    }
  }

  float bo[2];
#pragma unroll
  for (int nt = 0; nt < 2; nt++) {
    int n = wn * 32 + nt * 16 + l15;
    bo[nt] = (n < KT) ? bf2f(b_out[n]) : 0.f;
  }
#pragma unroll
  for (int mt = 0; mt < 4; mt++)
#pragma unroll
    for (int nt = 0; nt < 2; nt++) {
      int n = wn * 32 + nt * 16 + l15;
      if (n < KT) {
#pragma unroll
        for (int r = 0; r < 4; r++) {
          int m = bm * 128 + wm * 64 + mt * 16 + q * 4 + r;
          emit[(size_t)m * KT + n] = acc[mt][nt][r] + bo[nt];
        }
      }
    }
}

// ---------------------------------------------------------------- CRF forward
__global__ __launch_bounds__(256) void crf_kernel(
    const float* __restrict__ emit, const unsigned short* __restrict__ trans,
    const unsigned int* __restrict__ flag, void* __restrict__ out) {
  const int tid = threadIdx.x;
  const int wv = tid >> 6, lane = tid & 63;
  const int b = blockIdx.x * 4 + wv;
  const int jj = (lane < KT) ? lane : (KT - 1);

  float tr[KT];
  float mj = -1e30f;
#pragma unroll
  for (int i = 0; i < KT; i++) {
    tr[i] = bf2f(trans[jj * KT + i]);
    mj = fmaxf(mj, tr[i]);
  }
  float et[KT];
#pragma unroll
  for (int i = 0; i < KT; i++) et[i] = __expf(tr[i] - mj);
  float tr_stop = bf2f(trans[(KT - 1) * KT + jj]);

  float alpha = (lane == 0) ? 0.f : -1e30f;
  float e_next = emit[(size_t)b * KT + jj];

  for (int t = 0; t < T_; t++) {
    float e_cur = e_next;
    if (t < T_ - 1) e_next = emit[((size_t)(t + 1) * B_ + b) * KT + jj];
    float M = alpha;
#pragma unroll
    for (int off = 32; off; off >>= 1) M = fmaxf(M, __shfl_xor(M, off, 64));
    float p = __expf(alpha - M);
    float s = 0.f;
#pragma unroll
    for (int i = 0; i < KT; i++) {
      float pi = __uint_as_float(__builtin_amdgcn_readlane(__float_as_uint(p), i));
      s = __builtin_fmaf(et[i], pi, s);
    }
    float an = e_cur + mj + M + __logf(s);
    alpha = (lane < KT) ? an : -1e30f;
  }

  float v = (lane < KT) ? (alpha + tr_stop) : -1e30f;
  float M2 = v;
#pragma unroll
  for (int off = 32; off; off >>= 1) M2 = fmaxf(M2, __shfl_xor(M2, off, 64));
  float s2 = (lane < KT) ? __expf(v - M2) : 0.f;
#pragma unroll
  for (int off = 32; off; off >>= 1) s2 += __shfl_xor(s2, off, 64);
  float lz = M2 + __logf(s2);
  if (lane == 0) {
    if (*flag) ((unsigned short*)out)[b] = f2bf(lz);
    else ((float*)out)[b] = lz;
  }
}

// ---------------------------------------------------------------- launch
extern "C" void kernel_launch(void* const* d_in, const int* in_sizes, int n_in,
                              void* d_out, int out_size, void* d_ws, size_t ws_size,
                              hipStream_t stream) {
  const int* tokens = (const int*)d_in[0];
  const void* embed = d_in[1];
  const void* wih_f = d_in[2];
  const void* whh_f = d_in[3];
  const void* b_f = d_in[4];
  const void* wih_b = d_in[5];
  const void* whh_b = d_in[6];
  const void* b_b = d_in[7];
  const void* w_enc = d_in[8];
  const void* b_enc = d_in[9];
  const void* w_out = d_in[10];
  const void* b_out = d_in[11];
  const void* trans = d_in[12];

  char* ws = (char*)d_ws;
  // counters: 8 buckets x 1024 dwords (bucket-major; [bucket][dir][step]) = 32 KB
  unsigned int* cnts = (unsigned int*)ws;
  unsigned int* pflag = (unsigned int*)(ws + 262144);            // 256 B
  unsigned short* xbuf = (unsigned short*)(ws + 262400);         // 16 MB
  unsigned short* hf = (unsigned short*)(ws + 17039616);         // 32 MB
  unsigned short* hb = (unsigned short*)(ws + 50594048);         // 32 MB
  unsigned short* states = (unsigned short*)(ws + 84148480);     // 32 MB
  float* emit = (float*)(ws + 117702912);                        // 6.55 MB
  unsigned short* canon = (unsigned short*)(ws + 124256512);     // 7.4 MB

  unsigned short* c_wih_f = canon + 0;
  unsigned short* c_whh_f = canon + 524288;
  unsigned short* c_b_f   = canon + 1572864;
  unsigned short* c_wih_b = canon + 1574912;
  unsigned short* c_whh_b = canon + 2099200;
  unsigned short* c_b_b   = canon + 3147776;
  unsigned short* c_w_enc = canon + 3149824;
  unsigned short* c_b_enc = canon + 3674112;
  unsigned short* c_w_out = canon + 3674624;
  unsigned short* c_b_out = canon + 3700224;
  unsigned short* c_trans = canon + 3700352;

  hipMemsetAsync(cnts, 0, 8 * 1024 * sizeof(unsigned int), stream);
  probe_kernel<<<1, 64, 0, stream>>>((const unsigned short*)embed, pflag);

  CvtPack pk;
  pk.a[0]  = {wih_f, c_wih_f, 524288};
  pk.a[1]  = {whh_f, c_whh_f, 1048576};
  pk.a[2]  = {b_f,   c_b_f,   2048};
  pk.a[3]  = {wih_b, c_wih_b, 524288};
  pk.a[4]  = {whh_b, c_whh_b, 1048576};
  pk.a[5]  = {b_b,   c_b_b,   2048};
  pk.a[6]  = {w_enc, c_w_enc, 524288};
  pk.a[7]  = {b_enc, c_b_enc, 512};
  pk.a[8]  = {w_out, c_w_out, 25600};
  pk.a[9]  = {b_out, c_b_out, 50};
  pk.a[10] = {trans, c_trans, 2500};
  convert_kernel<<<dim3(512, 11), 256, 0, stream>>>(pk, pflag);

  embed_kernel<<<(T_ * B_) / 8, 256, 0, stream>>>(tokens, embed, pflag, xbuf);
  lstm_kernel<<<64, 256, 0, stream>>>(c_whh_f, c_wih_f, c_b_f,
                                      c_whh_b, c_wih_b, c_b_b,
                                      xbuf, hf, hb, cnts);
  enc_kernel<<<dim3(256, 4), 256, 0, stream>>>(hf, hb, c_w_enc, c_b_enc, states);
  emit_kernel<<<256, 256, 0, stream>>>(states, c_w_out, c_b_out, emit);
  crf_kernel<<<16, 256, 0, stream>>>(emit, c_trans, pflag, d_out);
}

// Round 6
// 2789.460 us; speedup vs baseline: 2.3765x; 1.4679x over previous
//
#include <hip/hip_runtime.h>
#include <stdint.h>

#define T_ 512
#define B_ 64
#define E_ 256
#define H_ 512
#define KT 50

typedef __attribute__((ext_vector_type(8))) short bf16x8;
typedef __attribute__((ext_vector_type(4))) float f32x4;
typedef __attribute__((ext_vector_type(4))) int i32x4;

#define MFMA16(a,b,c) __builtin_amdgcn_mfma_f32_16x16x32_bf16((a),(b),(c),0,0,0)

static __device__ __forceinline__ float bf2f(unsigned short v) {
  unsigned int u = ((unsigned int)v) << 16; float f; __builtin_memcpy(&f, &u, 4); return f;
}
static __device__ __forceinline__ unsigned short f2bf(float f) {
  unsigned int u; __builtin_memcpy(&u, &f, 4);
  u += 0x7fffu + ((u >> 16) & 1u);
  return (unsigned short)(u >> 16);
}
static __device__ __forceinline__ float sigm(float x) { return 1.f / (1.f + __expf(-x)); }
static __device__ __forceinline__ float tanh_(float x) { return 2.f / (1.f + __expf(-2.f * x)) - 1.f; }

// device-scope (MALL) dword load, self-waiting — for single-word polls
static __device__ __forceinline__ unsigned int load_dw_dev(const unsigned int* p) {
  unsigned int v;
  asm volatile("global_load_dword %0, %1, off sc0 sc1\n\ts_waitcnt vmcnt(0)"
               : "=v"(v) : "v"(p) : "memory");
  return v;
}

// ------------------------------------------------------------- dtype probe
__global__ void probe_kernel(const unsigned short* __restrict__ e,
                             unsigned int* __restrict__ flag) {
  int lane = threadIdx.x & 63;
  float a = fabsf(bf2f(e[2 * lane]));
  int good = (a >= 1e-8f && a <= 4.0f);
  unsigned long long m = __ballot(good);
  if (threadIdx.x == 0) flag[0] = (__popcll(m) >= 48) ? 1u : 0u;
}

// ------------------------------------------------------------- canonicalize
struct CvtArgs { const void* src; unsigned short* dst; int n; };
struct CvtPack { CvtArgs a[11]; };

__global__ __launch_bounds__(256) void convert_kernel(CvtPack p,
                                                      const unsigned int* __restrict__ flag) {
  CvtArgs c = p.a[blockIdx.y];
  int i = (blockIdx.x * 256 + threadIdx.x) * 8;
  if (i >= c.n) return;
  int isbf = *flag;
  if (i + 8 <= c.n) {
    if (isbf) {
      *(i32x4*)(c.dst + i) = *(const i32x4*)((const unsigned short*)c.src + i);
    } else {
      const float* s = (const float*)c.src;
      float4 a0 = *(const float4*)(s + i);
      float4 a1 = *(const float4*)(s + i + 4);
      unsigned short o[8] = {f2bf(a0.x), f2bf(a0.y), f2bf(a0.z), f2bf(a0.w),
                             f2bf(a1.x), f2bf(a1.y), f2bf(a1.z), f2bf(a1.w)};
      *(i32x4*)(c.dst + i) = *(i32x4*)o;
    }
  } else {
    for (int j = 0; j < 8; j++) {
      if (i + j < c.n) {
        c.dst[i + j] = isbf ? ((const unsigned short*)c.src)[i + j]
                            : f2bf(((const float*)c.src)[i + j]);
      }
    }
  }
}

// ---------------------------------------------------------------- embedding
__global__ __launch_bounds__(256) void embed_kernel(
    const int* __restrict__ tokens, const void* __restrict__ embed,
    const unsigned int* __restrict__ flag, unsigned short* __restrict__ x) {
  int tid = threadIdx.x;
  int row = blockIdx.x * 8 + (tid >> 5);   // row = t*64+b, 32768 rows
  int l = tid & 31;
  int tok = tokens[row];
  if (*flag) {
    const unsigned short* e = (const unsigned short*)embed;
    *(i32x4*)(x + (size_t)row * E_ + l * 8) =
        *(const i32x4*)(e + (size_t)tok * E_ + l * 8);
  } else {
    const float* e = (const float*)embed + (size_t)tok * E_ + l * 8;
    float4 a0 = *(const float4*)e;
    float4 a1 = *(const float4*)(e + 4);
    unsigned short o[8] = {f2bf(a0.x), f2bf(a0.y), f2bf(a0.z), f2bf(a0.w),
                           f2bf(a1.x), f2bf(a1.y), f2bf(a1.z), f2bf(a1.w)};
    *(i32x4*)(x + (size_t)row * E_ + l * 8) = *(i32x4*)o;
  }
}

// ---------------------------------------------------------------- BiLSTM
// 64 blocks: dir = bid&1, wg = bid>>1 (32 WGs/dir, 16 units each = 64 gate
// rows). Weights pinned in VGPRs (24 A-frags/wave). h FRAGMENT-NATIVE:
// dword = t*16384 + slab*256 + b*4 + j2 (slab = kc*4+q), so publish and
// gather are lane-coalesced. Transport (all device-scope sc0 sc1 / MALL):
//   publish: one asm block, 2x dwordx4 stores + single vmcnt(0) drain
//   tag:     monotonic per-producer word (64B-separated), value step+1
//   detect:  one poller wave reads all 32 tags in ONE 32-lane load / iter
//   gather:  one asm block, 16x dwordx4 loads + single vmcnt(0)
__global__ __launch_bounds__(256, 1) void lstm_kernel(
    const unsigned short* __restrict__ whh_f, const unsigned short* __restrict__ wih_f,
    const unsigned short* __restrict__ bias_f,
    const unsigned short* __restrict__ whh_b, const unsigned short* __restrict__ wih_b,
    const unsigned short* __restrict__ bias_b,
    const unsigned short* __restrict__ x,
    unsigned short* __restrict__ hf, unsigned short* __restrict__ hb,
    unsigned int* __restrict__ tags) {
  const int tid = threadIdx.x;
  const int wv = tid >> 6, lane = tid & 63, q = lane >> 4, l15 = lane & 15;
  const int bid = blockIdx.x;
  const int dir = bid & 1;
  const int wg = bid >> 1;            // 0..31 within direction
  const int u0 = wg * 16;

  const unsigned short* whh = dir ? whh_b : whh_f;
  const unsigned short* wih = dir ? wih_b : wih_f;
  const unsigned short* bvec = dir ? bias_b : bias_f;
  unsigned short* hbuf = dir ? hb : hf;
  unsigned int* tbase = tags + (size_t)dir * 512;  // 32 tags, 16-dword stride

  // ---- preload weight A-fragments: afrag[gate mt][k-chunk kl]
  bf16x8 afrag[4][6];
#pragma unroll
  for (int mt = 0; mt < 4; mt++) {
    int row = mt * H_ + u0 + l15;
#pragma unroll
    for (int kl = 0; kl < 6; kl++) {
      const unsigned short* p = (kl < 4)
          ? (whh + (size_t)row * H_ + (wv * 4 + kl) * 32 + q * 8)
          : (wih + (size_t)row * E_ + (wv * 2 + (kl - 4)) * 32 + q * 8);
      afrag[mt][kl] = *(const bf16x8*)p;
    }
  }

  const int eb = tid & 63;
  const int uu = tid >> 6;
  float bg[4][4];
#pragma unroll
  for (int s = 0; s < 4; s++) {
    int u = uu + 4 * s;
#pragma unroll
    for (int g = 0; g < 4; g++) bg[s][g] = bf2f(bvec[g * H_ + u0 + u]);
  }
  float cst[4] = {0.f, 0.f, 0.f, 0.f};

  __shared__ float pacc[4][64][66];
  __shared__ __align__(16) unsigned short h_out[64][16];
  __shared__ unsigned int go_word;
  if (tid == 0) go_word = 0;

  for (int step = 0; step < T_; step++) {
    const int t = dir ? (T_ - 1 - step) : step;
    f32x4 acc[4][4];
#pragma unroll
    for (int mt = 0; mt < 4; mt++)
#pragma unroll
      for (int nt = 0; nt < 4; nt++) acc[mt][nt] = (f32x4){0.f, 0.f, 0.f, 0.f};

    // x-part (independent of h — overlaps producer latency)
    {
      const unsigned short* xb = x + (size_t)t * B_ * E_;
#pragma unroll
      for (int kl = 4; kl < 6; kl++) {
        int ec = wv * 2 + (kl - 4);
#pragma unroll
        for (int nt = 0; nt < 4; nt++) {
          int b = nt * 16 + l15;
          bf16x8 bx = *(const bf16x8*)(xb + (size_t)b * E_ + ec * 32 + q * 8);
#pragma unroll
          for (int mt = 0; mt < 4; mt++)
            acc[mt][nt] = MFMA16(afrag[mt][kl], bx, acc[mt][nt]);
        }
      }
    }

    if (step > 0) {
      if (wv == 1) {  // poller: all 32 tags in one 32-lane device load
        const unsigned int* tp = tbase + (size_t)(lane & 31) * 16;
        for (;;) {
          unsigned int v = load_dw_dev(tp);
          unsigned long long m = __ballot((lane < 32) ? (v >= (unsigned)step) : 1);
          if (m == ~0ULL) break;
          __builtin_amdgcn_s_sleep(1);
        }
        __hip_atomic_store(&go_word, (unsigned int)step, __ATOMIC_RELAXED,
                           __HIP_MEMORY_SCOPE_WORKGROUP);
      } else {        // siblings spin on LDS (no fabric traffic)
        while (__hip_atomic_load(&go_word, __ATOMIC_RELAXED,
                                 __HIP_MEMORY_SCOPE_WORKGROUP) < (unsigned int)step)
          __builtin_amdgcn_s_sleep(1);
      }
      asm volatile("" ::: "memory");  // no hoisting of h loads above the wait

      const int tprev = dir ? (t + 1) : (t - 1);
      const unsigned int* hD = (const unsigned int*)hbuf + (size_t)tprev * 16384;

      // 16 device-scope dwordx4 loads, one batch, one vmcnt(0)
      const unsigned int* a0 = hD + ((wv * 4 + 0) * 4 + q) * 256 + l15 * 4;
      const unsigned int* a1 = hD + ((wv * 4 + 1) * 4 + q) * 256 + l15 * 4;
      const unsigned int* a2 = hD + ((wv * 4 + 2) * 4 + q) * 256 + l15 * 4;
      const unsigned int* a3 = hD + ((wv * 4 + 3) * 4 + q) * 256 + l15 * 4;
      i32x4 h00, h01, h02, h03, h10, h11, h12, h13;
      i32x4 h20, h21, h22, h23, h30, h31, h32, h33;
      asm volatile(
          "global_load_dwordx4 %0, %16, off sc0 sc1\n\t"
          "global_load_dwordx4 %1, %16, off offset:1024 sc0 sc1\n\t"
          "global_load_dwordx4 %2, %16, off offset:2048 sc0 sc1\n\t"
          "global_load_dwordx4 %3, %16, off offset:3072 sc0 sc1\n\t"
          "global_load_dwordx4 %4, %17, off sc0 sc1\n\t"
          "global_load_dwordx4 %5, %17, off offset:1024 sc0 sc1\n\t"
          "global_load_dwordx4 %6, %17, off offset:2048 sc0 sc1\n\t"
          "global_load_dwordx4 %7, %17, off offset:3072 sc0 sc1\n\t"
          "global_load_dwordx4 %8, %18, off sc0 sc1\n\t"
          "global_load_dwordx4 %9, %18, off offset:1024 sc0 sc1\n\t"
          "global_load_dwordx4 %10, %18, off offset:2048 sc0 sc1\n\t"
          "global_load_dwordx4 %11, %18, off offset:3072 sc0 sc1\n\t"
          "global_load_dwordx4 %12, %19, off sc0 sc1\n\t"
          "global_load_dwordx4 %13, %19, off offset:1024 sc0 sc1\n\t"
          "global_load_dwordx4 %14, %19, off offset:2048 sc0 sc1\n\t"
          "global_load_dwordx4 %15, %19, off offset:3072 sc0 sc1\n\t"
          "s_waitcnt vmcnt(0)"
          : "=&v"(h00), "=&v"(h01), "=&v"(h02), "=&v"(h03),
            "=&v"(h10), "=&v"(h11), "=&v"(h12), "=&v"(h13),
            "=&v"(h20), "=&v"(h21), "=&v"(h22), "=&v"(h23),
            "=&v"(h30), "=&v"(h31), "=&v"(h32), "=&v"(h33)
          : "v"(a0), "v"(a1), "v"(a2), "v"(a3)
          : "memory");
      i32x4 hr4[16] = {h00, h01, h02, h03, h10, h11, h12, h13,
                       h20, h21, h22, h23, h30, h31, h32, h33};
#pragma unroll
      for (int kl = 0; kl < 4; kl++) {
#pragma unroll
        for (int nt = 0; nt < 4; nt++) {
          bf16x8 bh;
          __builtin_memcpy(&bh, &hr4[kl * 4 + nt], 16);
#pragma unroll
          for (int mt = 0; mt < 4; mt++)
            acc[mt][nt] = MFMA16(afrag[mt][kl], bh, acc[mt][nt]);
        }
      }
    }

    __syncthreads();
#pragma unroll
    for (int mt = 0; mt < 4; mt++)
#pragma unroll
      for (int nt = 0; nt < 4; nt++)
#pragma unroll
        for (int r = 0; r < 4; r++)
          pacc[wv][mt * 16 + q * 4 + r][nt * 16 + l15] = acc[mt][nt][r];
    __syncthreads();

#pragma unroll
    for (int s = 0; s < 4; s++) {
      int u = uu + 4 * s;
      float gi = bg[s][0], gf = bg[s][1], gg = bg[s][2], og = bg[s][3];
#pragma unroll
      for (int w = 0; w < 4; w++) {
        gi += pacc[w][u][eb];
        gf += pacc[w][16 + u][eb];
        gg += pacc[w][32 + u][eb];
        og += pacc[w][48 + u][eb];
      }
      float cn = sigm(gf) * cst[s] + sigm(gi) * tanh_(gg);
      cst[s] = cn;
      h_out[eb][u] = f2bf(sigm(og) * tanh_(cn));
    }
    __syncthreads();

    if (wv == 0) {  // publish: 2 vec stores + one drain, then tag (monotonic)
      unsigned int* gp = (unsigned int*)hbuf + (size_t)t * 16384 + wg * 512 + lane * 4;
      i32x4 v0 = *(const i32x4*)&h_out[lane][0];
      i32x4 v1 = *(const i32x4*)&h_out[lane][8];
      asm volatile(
          "global_store_dwordx4 %0, %1, off sc0 sc1\n\t"
          "global_store_dwordx4 %0, %2, off offset:1024 sc0 sc1\n\t"
          "s_waitcnt vmcnt(0)"
          :: "v"(gp), "v"(v0), "v"(v1) : "memory");
      if (lane == 0) {
        unsigned int* tp = tbase + (size_t)wg * 16;
        unsigned int tv = (unsigned int)(step + 1);
        asm volatile("global_store_dword %0, %1, off sc0 sc1"
                     :: "v"(tp), "v"(tv) : "memory");
      }
    }
  }
}

// ---------------------------------------------------------------- encoder GEMM
// states = tanh([hf|hb] @ w_enc^T + b_enc): M=32768, K=1024, N=512.
// hf/hb fragment-native: dword = t*16384 + (u>>3)*256 + b*4 + j2
__global__ __launch_bounds__(256) void enc_kernel(
    const unsigned short* __restrict__ hf, const unsigned short* __restrict__ hb,
    const unsigned short* __restrict__ w_enc, const unsigned short* __restrict__ b_enc,
    unsigned short* __restrict__ states) {
  const int tid = threadIdx.x;
  const int bm = blockIdx.x, bn = blockIdx.y;
  const int wv = tid >> 6, lane = tid & 63, q = lane >> 4, l15 = lane & 15;
  const int wm = wv >> 1, wn = wv & 1;

  __shared__ __align__(16) unsigned short a_lds[128][72];
  __shared__ __align__(16) unsigned short b_lds[128][72];
  __shared__ __align__(16) unsigned short st_lds[128][136];

  f32x4 acc[4][4];
#pragma unroll
  for (int mt = 0; mt < 4; mt++)
#pragma unroll
    for (int nt = 0; nt < 4; nt++) acc[mt][nt] = (f32x4){0.f, 0.f, 0.f, 0.f};

  for (int c = 0; c < 16; c++) {
    const unsigned short* asrc = (c < 8) ? hf : hb;
    int kof = (c & 7) * 64;
#pragma unroll
    for (int p = 0; p < 4; p++) {
      int u_ = tid + p * 256;
      int r = u_ >> 3, wu = u_ & 7;
      int grow = bm * 128 + r;   // t = grow>>6, b = grow&63
      *(i32x4*)&a_lds[r][wu * 8] =
          *(const i32x4*)((const unsigned int*)asrc + (size_t)(grow >> 6) * 16384 +
                          (size_t)((kof >> 3) + wu) * 256 + (grow & 63) * 4);
      *(i32x4*)&b_lds[r][wu * 8] =
          *(const i32x4*)(w_enc + (size_t)(bn * 128 + r) * 1024 + c * 64 + wu * 8);
    }
    __syncthreads();
#pragma unroll
    for (int kk = 0; kk < 64; kk += 32) {
      bf16x8 af[4], bfr[4];
#pragma unroll
      for (int mt = 0; mt < 4; mt++)
        af[mt] = *(const bf16x8*)&a_lds[wm * 64 + mt * 16 + l15][kk + q * 8];
#pragma unroll
      for (int nt = 0; nt < 4; nt++)
        bfr[nt] = *(const bf16x8*)&b_lds[wn * 64 + nt * 16 + l15][kk + q * 8];
#pragma unroll
      for (int mt = 0; mt < 4; mt++)
#pragma unroll
        for (int nt = 0; nt < 4; nt++) acc[mt][nt] = MFMA16(af[mt], bfr[nt], acc[mt][nt]);
    }
    __syncthreads();
  }

  float be[4];
#pragma unroll
  for (int nt = 0; nt < 4; nt++)
    be[nt] = bf2f(b_enc[bn * 128 + wn * 64 + nt * 16 + l15]);
#pragma unroll
  for (int mt = 0; mt < 4; mt++)
#pragma unroll
    for (int nt = 0; nt < 4; nt++)
#pragma unroll
      for (int r = 0; r < 4; r++) {
        float v = tanh_(acc[mt][nt][r] + be[nt]);
        st_lds[wm * 64 + mt * 16 + q * 4 + r][wn * 64 + nt * 16 + l15] = f2bf(v);
      }
  __syncthreads();
#pragma unroll
  for (int p = 0; p < 8; p++) {
    int u_ = tid + p * 256;
    int r = u_ >> 4, w = u_ & 15;
    *(i32x4*)(states + (size_t)(bm * 128 + r) * H_ + bn * 128 + w * 8) =
        *(const i32x4*)&st_lds[r][w * 8];
  }
}

// ---------------------------------------------------------------- emit GEMM
// emit = states @ w_out^T + b_out: M=32768, K=512, N=50 (padded 64), fp32 out
__global__ __launch_bounds__(256) void emit_kernel(
    const unsigned short* __restrict__ states, const unsigned short* __restrict__ w_out,
    const unsigned short* __restrict__ b_out, float* __restrict__ emit) {
  const int tid = threadIdx.x;
  const int bm = blockIdx.x;
  const int wv = tid >> 6, lane = tid & 63, q = lane >> 4, l15 = lane & 15;
  const int wm = wv >> 1, wn = wv & 1;

  __shared__ __align__(16) unsigned short wo_lds[64][520];
  __shared__ __align__(16) unsigned short a_lds[128][72];

#pragma unroll
  for (int p = 0; p < 16; p++) {
    int u = tid + p * 256;
    int r = u >> 6, wu = u & 63;
    i32x4 v = {0, 0, 0, 0};
    if (r < KT) v = *(const i32x4*)(w_out + (size_t)r * H_ + wu * 8);
    *(i32x4*)&wo_lds[r][wu * 8] = v;
  }

  f32x4 acc[4][2];
#pragma unroll
  for (int mt = 0; mt < 4; mt++)
#pragma unroll
    for (int nt = 0; nt < 2; nt++) acc[mt][nt] = (f32x4){0.f, 0.f, 0.f, 0.f};

  for (int c = 0; c < 8; c++) {
    __syncthreads();
#pragma unroll
    for (int p = 0; p < 4; p++) {
      int u = tid + p * 256;
      int r = u >> 3, wu = u & 7;
      *(i32x4*)&a_lds[r][wu * 8] =
          *(const i32x4*)(states + (size_t)(bm * 128 + r) * H_ + c * 64 + wu * 8);
    }
    __syncthreads();
#pragma unroll
    for (int kk = 0; kk < 64; kk += 32) {
      bf16x8 af[4], bfr[2];
#pragma unroll
      for (int mt = 0; mt < 4; mt++)
        af[mt] = *(const bf16x8*)&a_lds[wm * 64 + mt * 16 + l15][kk + q * 8];
#pragma unroll
      for (int nt = 0; nt < 2; nt++)
        bfr[nt] = *(const bf16x8*)&wo_lds[wn * 32 + nt * 16 + l15][c * 64 + kk + q * 8];
#pragma unroll
      for (int mt = 0; mt < 4; mt++)
#pragma unroll
        for (int nt = 0; nt < 2; nt++) acc[mt][nt] = MFMA16(af[mt], bfr[nt], acc[mt][nt]);
    }
  }

  float bo[2];
#pragma unroll
  for (int nt = 0; nt < 2; nt++) {
    int n = wn * 32 + nt * 16 + l15;
    bo[nt] = (n < KT) ? bf2f(b_out[n]) : 0.f;
  }
#pragma unroll
  for (int mt = 0; mt < 4; mt++)
#pragma unroll
    for (int nt = 0; nt < 2; nt++) {
      int n = wn * 32 + nt * 16 + l15;
      if (n < KT) {
#pragma unroll
        for (int r = 0; r < 4; r++) {
          int m = bm * 128 + wm * 64 + mt * 16 + q * 4 + r;
          emit[(size_t)m * KT + n] = acc[mt][nt][r] + bo[nt];
        }
      }
    }
}

// ---------------------------------------------------------------- CRF forward
__global__ __launch_bounds__(256) void crf_kernel(
    const float* __restrict__ emit, const unsigned short* __restrict__ trans,
    const unsigned int* __restrict__ flag, void* __restrict__ out) {
  const int tid = threadIdx.x;
  const int wv = tid >> 6, lane = tid & 63;
  const int b = blockIdx.x * 4 + wv;
  const int jj = (lane < KT) ? lane : (KT - 1);

  float tr[KT];
  float mj = -1e30f;
#pragma unroll
  for (int i = 0; i < KT; i++) {
    tr[i] = bf2f(trans[jj * KT + i]);
    mj = fmaxf(mj, tr[i]);
  }
  float et[KT];
#pragma unroll
  for (int i = 0; i < KT; i++) et[i] = __expf(tr[i] - mj);
  float tr_stop = bf2f(trans[(KT - 1) * KT + jj]);

  float alpha = (lane == 0) ? 0.f : -1e30f;
  float e_next = emit[(size_t)b * KT + jj];

  for (int t = 0; t < T_; t++) {
    float e_cur = e_next;
    if (t < T_ - 1) e_next = emit[((size_t)(t + 1) * B_ + b) * KT + jj];
    float M = alpha;
#pragma unroll
    for (int off = 32; off; off >>= 1) M = fmaxf(M, __shfl_xor(M, off, 64));
    float p = __expf(alpha - M);
    float s = 0.f;
#pragma unroll
    for (int i = 0; i < KT; i++) {
      float pi = __uint_as_float(__builtin_amdgcn_readlane(__float_as_uint(p), i));
      s = __builtin_fmaf(et[i], pi, s);
    }
    float an = e_cur + mj + M + __logf(s);
    alpha = (lane < KT) ? an : -1e30f;
  }

  float v = (lane < KT) ? (alpha + tr_stop) : -1e30f;
  float M2 = v;
#pragma unroll
  for (int off = 32; off; off >>= 1) M2 = fmaxf(M2, __shfl_xor(M2, off, 64));
  float s2 = (lane < KT) ? __expf(v - M2) : 0.f;
#pragma unroll
  for (int off = 32; off; off >>= 1) s2 += __shfl_xor(s2, off, 64);
  float lz = M2 + __logf(s2);
  if (lane == 0) {
    if (*flag) ((unsigned short*)out)[b] = f2bf(lz);
    else ((float*)out)[b] = lz;
  }
}

// ---------------------------------------------------------------- launch
extern "C" void kernel_launch(void* const* d_in, const int* in_sizes, int n_in,
                              void* d_out, int out_size, void* d_ws, size_t ws_size,
                              hipStream_t stream) {
  const int* tokens = (const int*)d_in[0];
  const void* embed = d_in[1];
  const void* wih_f = d_in[2];
  const void* whh_f = d_in[3];
  const void* b_f = d_in[4];
  const void* wih_b = d_in[5];
  const void* whh_b = d_in[6];
  const void* b_b = d_in[7];
  const void* w_enc = d_in[8];
  const void* b_enc = d_in[9];
  const void* w_out = d_in[10];
  const void* b_out = d_in[11];
  const void* trans = d_in[12];

  char* ws = (char*)d_ws;
  // tags: [dir][wg] monotonic words, 16-dword (64B) stride = 4 KB total
  unsigned int* tags = (unsigned int*)ws;
  unsigned int* pflag = (unsigned int*)(ws + 262144);            // 256 B
  unsigned short* xbuf = (unsigned short*)(ws + 262400);         // 16 MB
  unsigned short* hf = (unsigned short*)(ws + 17039616);         // 32 MB
  unsigned short* hb = (unsigned short*)(ws + 50594048);         // 32 MB
  unsigned short* states = (unsigned short*)(ws + 84148480);     // 32 MB
  float* emit = (float*)(ws + 117702912);                        // 6.55 MB
  unsigned short* canon = (unsigned short*)(ws + 124256512);     // 7.4 MB

  unsigned short* c_wih_f = canon + 0;
  unsigned short* c_whh_f = canon + 524288;
  unsigned short* c_b_f   = canon + 1572864;
  unsigned short* c_wih_b = canon + 1574912;
  unsigned short* c_whh_b = canon + 2099200;
  unsigned short* c_b_b   = canon + 3147776;
  unsigned short* c_w_enc = canon + 3149824;
  unsigned short* c_b_enc = canon + 3674112;
  unsigned short* c_w_out = canon + 3674624;
  unsigned short* c_b_out = canon + 3700224;
  unsigned short* c_trans = canon + 3700352;

  hipMemsetAsync(tags, 0, 4096, stream);
  probe_kernel<<<1, 64, 0, stream>>>((const unsigned short*)embed, pflag);

  CvtPack pk;
  pk.a[0]  = {wih_f, c_wih_f, 524288};
  pk.a[1]  = {whh_f, c_whh_f, 1048576};
  pk.a[2]  = {b_f,   c_b_f,   2048};
  pk.a[3]  = {wih_b, c_wih_b, 524288};
  pk.a[4]  = {whh_b, c_whh_b, 1048576};
  pk.a[5]  = {b_b,   c_b_b,   2048};
  pk.a[6]  = {w_enc, c_w_enc, 524288};
  pk.a[7]  = {b_enc, c_b_enc, 512};
  pk.a[8]  = {w_out, c_w_out, 25600};
  pk.a[9]  = {b_out, c_b_out, 50};
  pk.a[10] = {trans, c_trans, 2500};
  convert_kernel<<<dim3(512, 11), 256, 0, stream>>>(pk, pflag);

  embed_kernel<<<(T_ * B_) / 8, 256, 0, stream>>>(tokens, embed, pflag, xbuf);
  lstm_kernel<<<64, 256, 0, stream>>>(c_whh_f, c_wih_f, c_b_f,
                                      c_whh_b, c_wih_b, c_b_b,
                                      xbuf, hf, hb, tags);
  enc_kernel<<<dim3(256, 4), 256, 0, stream>>>(hf, hb, c_w_enc, c_b_enc, states);
  emit_kernel<<<256, 256, 0, stream>>>(states, c_w_out, c_b_out, emit);
  crf_kernel<<<16, 256, 0, stream>>>(emit, c_trans, pflag, d_out);
}